// Round 1
// baseline (3439.606 us; speedup 1.0000x reference)
//
#include <hip/hip_runtime.h>
#include <math.h>

// Round 0: correct fp32 baseline for RvNN (N=4096, D=5000, H=512, C=4, L=8).
//
// Exploits the level mask: only ~N/L rows are active per level, so per-level
// matmuls are gathered to active rows:
//   x_hat = x @ E_w^T                    (4096x5000x512)  21.0 GF
//   xr/xz/xh = x_hat @ W*^T              (3x 4096x512x512) 6.4 GF
//   per level j=7..0:
//     hs   = adj[rows_j,:] @ h           (~512x4096x512)   2.1 GF
//     r,z  = sig(x*+hs@U*^T), t=hs*r     (2x ~512^3)
//     hhat = tanh(xh+t@Uh^T); h[rows_j]=(1-z)hs+z*hhat
//   out = h @ dec_w^T + dec_b
// All fp32 vector FMA (no MFMA this round — correctness first; the z-gate
// saturation makes plain-bf16 gate matmuls borderline vs the 2%-of-absmax
// threshold; later rounds use bf16 MFMA for the big matmuls + split precision
// for gates).

#define TM 64
#define TN 64
#define KT 16

__device__ __forceinline__ float sigf(float x) { return 1.0f / (1.0f + __expf(-x)); }

__device__ __forceinline__ void fma16(float (&acc)[4][4], float4 a, float4 b) {
  acc[0][0] = fmaf(a.x, b.x, acc[0][0]);
  acc[0][1] = fmaf(a.x, b.y, acc[0][1]);
  acc[0][2] = fmaf(a.x, b.z, acc[0][2]);
  acc[0][3] = fmaf(a.x, b.w, acc[0][3]);
  acc[1][0] = fmaf(a.y, b.x, acc[1][0]);
  acc[1][1] = fmaf(a.y, b.y, acc[1][1]);
  acc[1][2] = fmaf(a.y, b.z, acc[1][2]);
  acc[1][3] = fmaf(a.y, b.w, acc[1][3]);
  acc[2][0] = fmaf(a.z, b.x, acc[2][0]);
  acc[2][1] = fmaf(a.z, b.y, acc[2][1]);
  acc[2][2] = fmaf(a.z, b.z, acc[2][2]);
  acc[2][3] = fmaf(a.z, b.w, acc[2][3]);
  acc[3][0] = fmaf(a.w, b.x, acc[3][0]);
  acc[3][1] = fmaf(a.w, b.y, acc[3][1]);
  acc[3][2] = fmaf(a.w, b.z, acc[3][2]);
  acc[3][3] = fmaf(a.w, b.w, acc[3][3]);
}

// guarded float4 load for K-tail (only evaluates in-bounds lanes)
__device__ __forceinline__ float4 ld4g(const float* p, int kidx, int K) {
  float4 v;
  v.x = (kidx + 0 < K) ? p[0] : 0.0f;
  v.y = (kidx + 1 < K) ? p[1] : 0.0f;
  v.z = (kidx + 2 < K) ? p[2] : 0.0f;
  v.w = (kidx + 3 < K) ? p[3] : 0.0f;
  return v;
}

// -------- build per-level row lists --------
__global__ __launch_bounds__(256) void build_lists(const int* __restrict__ level,
                                                   int* __restrict__ counts,
                                                   int* __restrict__ rows, int N) {
  int i = blockIdx.x * blockDim.x + threadIdx.x;
  if (i < N) {
    int j = level[i];
    int p = atomicAdd(&counts[j], 1);
    rows[(size_t)j * N + p] = i;
  }
}

// -------- C = A @ B^T, batched over up to 3 (B,C) pairs via blockIdx.z -----
// A [M,K] row-major, B [Ncol,K] row-major, C [M,Ncol]. M%TM==0, Ncol%TN==0.
__global__ __launch_bounds__(256) void gemm_tn3(
    const float* __restrict__ A, const float* __restrict__ Ba,
    const float* __restrict__ Bb, const float* __restrict__ Bc,
    float* __restrict__ Ca, float* __restrict__ Cb, float* __restrict__ Cc,
    int M, int Ncol, int K) {
  const float* B = (blockIdx.z == 0) ? Ba : ((blockIdx.z == 1) ? Bb : Bc);
  float* C = (blockIdx.z == 0) ? Ca : ((blockIdx.z == 1) ? Cb : Cc);
  __shared__ float As[KT][TM];
  __shared__ float Bs[KT][TN];
  const int tid = threadIdx.x;
  const int tx = tid & 15, ty = tid >> 4;
  const int lrow = tid >> 2, lk = (tid & 3) << 2;
  const int bm = blockIdx.x * TM, bn = blockIdx.y * TN;
  float acc[4][4] = {};
  for (int k0 = 0; k0 < K; k0 += KT) {
    const bool full = (k0 + KT <= K);
    {
      const float* ap = A + (size_t)(bm + lrow) * K + (k0 + lk);
      float4 v = full ? *reinterpret_cast<const float4*>(ap) : ld4g(ap, k0 + lk, K);
      As[lk + 0][lrow] = v.x; As[lk + 1][lrow] = v.y;
      As[lk + 2][lrow] = v.z; As[lk + 3][lrow] = v.w;
    }
    {
      const float* bp = B + (size_t)(bn + lrow) * K + (k0 + lk);
      float4 v = full ? *reinterpret_cast<const float4*>(bp) : ld4g(bp, k0 + lk, K);
      Bs[lk + 0][lrow] = v.x; Bs[lk + 1][lrow] = v.y;
      Bs[lk + 2][lrow] = v.z; Bs[lk + 3][lrow] = v.w;
    }
    __syncthreads();
#pragma unroll
    for (int k = 0; k < KT; ++k) {
      float4 av = *reinterpret_cast<const float4*>(&As[k][ty << 2]);
      float4 bv = *reinterpret_cast<const float4*>(&Bs[k][tx << 2]);
      fma16(acc, av, bv);
    }
    __syncthreads();
  }
  float* cp = C + (size_t)(bm + (ty << 2)) * Ncol + bn + (tx << 2);
#pragma unroll
  for (int i = 0; i < 4; ++i) {
    float4 st = make_float4(acc[i][0], acc[i][1], acc[i][2], acc[i][3]);
    *reinterpret_cast<float4*>(cp + (size_t)i * Ncol) = st;
  }
}

// -------- hs[p,:] = adj[rows[p],:] @ h   (A rows gathered, B=h is [K,H]) ---
__global__ __launch_bounds__(256) void agg_gather(
    const float* __restrict__ adj, const float* __restrict__ h,
    const int* __restrict__ rows, const int* __restrict__ counts, int lvl,
    int N, int H, float* __restrict__ hs) {
  const int cnt = counts[lvl];
  const int bm = blockIdx.x * TM;
  if (bm >= cnt) return;
  const int* rl = rows + (size_t)lvl * N;
  __shared__ float As[KT][TM];
  __shared__ float Bs[KT][TN];
  const int tid = threadIdx.x;
  const int tx = tid & 15, ty = tid >> 4;
  const int lrow = tid >> 2, lk = (tid & 3) << 2;   // A-tile loader mapping
  const int lkr = tid >> 4, lnc = (tid & 15) << 2;  // B-tile loader mapping
  const int bn = blockIdx.y * TN;
  const int p0 = bm + lrow;
  const int arow = rl[(p0 < cnt) ? p0 : 0];  // clamp: dup row0, never stored
  float acc[4][4] = {};
  for (int k0 = 0; k0 < N; k0 += KT) {  // K = N (4096), divisible by KT
    {
      float4 v = *reinterpret_cast<const float4*>(adj + (size_t)arow * N + k0 + lk);
      As[lk + 0][lrow] = v.x; As[lk + 1][lrow] = v.y;
      As[lk + 2][lrow] = v.z; As[lk + 3][lrow] = v.w;
    }
    {
      float4 v = *reinterpret_cast<const float4*>(h + (size_t)(k0 + lkr) * H + bn + lnc);
      *reinterpret_cast<float4*>(&Bs[lkr][lnc]) = v;
    }
    __syncthreads();
#pragma unroll
    for (int k = 0; k < KT; ++k) {
      float4 av = *reinterpret_cast<const float4*>(&As[k][ty << 2]);
      float4 bv = *reinterpret_cast<const float4*>(&Bs[k][tx << 2]);
      fma16(acc, av, bv);
    }
    __syncthreads();
  }
#pragma unroll
  for (int i = 0; i < 4; ++i) {
    int p = bm + (ty << 2) + i;
    if (p >= cnt) break;
    float4 st = make_float4(acc[i][0], acc[i][1], acc[i][2], acc[i][3]);
    *reinterpret_cast<float4*>(hs + (size_t)p * H + bn + (tx << 2)) = st;
  }
}

// -------- r,z gates: t = hs*sig(xr+hs@Ur^T), zb = sig(xz+hs@Uz^T) ----------
__global__ __launch_bounds__(256) void gates_rz(
    const float* __restrict__ hs, const float* __restrict__ Ur,
    const float* __restrict__ Uz, const float* __restrict__ xr,
    const float* __restrict__ xz, const int* __restrict__ rows,
    const int* __restrict__ counts, int lvl, int N, int H,
    float* __restrict__ tb, float* __restrict__ zb) {
  const int cnt = counts[lvl];
  const int bm = blockIdx.x * TM;
  if (bm >= cnt) return;
  const int* rl = rows + (size_t)lvl * N;
  __shared__ float As[KT][TM];
  __shared__ float Br[KT][TN];
  __shared__ float Bz[KT][TN];
  const int tid = threadIdx.x;
  const int tx = tid & 15, ty = tid >> 4;
  const int lrow = tid >> 2, lk = (tid & 3) << 2;
  const int bn = blockIdx.y * TN;
  const int p0 = bm + lrow;
  const int ar = (p0 < cnt) ? p0 : 0;
  float accR[4][4] = {};
  float accZ[4][4] = {};
  for (int k0 = 0; k0 < H; k0 += KT) {
    {
      float4 v = *reinterpret_cast<const float4*>(hs + (size_t)ar * H + k0 + lk);
      As[lk + 0][lrow] = v.x; As[lk + 1][lrow] = v.y;
      As[lk + 2][lrow] = v.z; As[lk + 3][lrow] = v.w;
    }
    {
      float4 v = *reinterpret_cast<const float4*>(Ur + (size_t)(bn + lrow) * H + k0 + lk);
      Br[lk + 0][lrow] = v.x; Br[lk + 1][lrow] = v.y;
      Br[lk + 2][lrow] = v.z; Br[lk + 3][lrow] = v.w;
    }
    {
      float4 v = *reinterpret_cast<const float4*>(Uz + (size_t)(bn + lrow) * H + k0 + lk);
      Bz[lk + 0][lrow] = v.x; Bz[lk + 1][lrow] = v.y;
      Bz[lk + 2][lrow] = v.z; Bz[lk + 3][lrow] = v.w;
    }
    __syncthreads();
#pragma unroll
    for (int k = 0; k < KT; ++k) {
      float4 av = *reinterpret_cast<const float4*>(&As[k][ty << 2]);
      float4 br = *reinterpret_cast<const float4*>(&Br[k][tx << 2]);
      float4 bz = *reinterpret_cast<const float4*>(&Bz[k][tx << 2]);
      fma16(accR, av, br);
      fma16(accZ, av, bz);
    }
    __syncthreads();
  }
#pragma unroll
  for (int i = 0; i < 4; ++i) {
    int p = bm + (ty << 2) + i;
    if (p >= cnt) break;
    int g = rl[p];
    int col = bn + (tx << 2);
    float4 xrv = *reinterpret_cast<const float4*>(xr + (size_t)g * H + col);
    float4 xzv = *reinterpret_cast<const float4*>(xz + (size_t)g * H + col);
    float4 hsv = *reinterpret_cast<const float4*>(hs + (size_t)p * H + col);
    float4 tv, zv;
    tv.x = hsv.x * sigf(xrv.x + accR[i][0]);
    tv.y = hsv.y * sigf(xrv.y + accR[i][1]);
    tv.z = hsv.z * sigf(xrv.z + accR[i][2]);
    tv.w = hsv.w * sigf(xrv.w + accR[i][3]);
    zv.x = sigf(xzv.x + accZ[i][0]);
    zv.y = sigf(xzv.y + accZ[i][1]);
    zv.z = sigf(xzv.z + accZ[i][2]);
    zv.w = sigf(xzv.w + accZ[i][3]);
    *reinterpret_cast<float4*>(tb + (size_t)p * H + col) = tv;
    *reinterpret_cast<float4*>(zb + (size_t)p * H + col) = zv;
  }
}

// -------- h-hat gate + state update: h[g,:] = (1-z)*hs + z*tanh(xh+t@Uh^T) -
__global__ __launch_bounds__(256) void gates_h(
    const float* __restrict__ tb, const float* __restrict__ Uh,
    const float* __restrict__ xh, const float* __restrict__ hs,
    const float* __restrict__ zb, const int* __restrict__ rows,
    const int* __restrict__ counts, int lvl, int N, int H,
    float* __restrict__ h) {
  const int cnt = counts[lvl];
  const int bm = blockIdx.x * TM;
  if (bm >= cnt) return;
  const int* rl = rows + (size_t)lvl * N;
  __shared__ float As[KT][TM];
  __shared__ float Bs[KT][TN];
  const int tid = threadIdx.x;
  const int tx = tid & 15, ty = tid >> 4;
  const int lrow = tid >> 2, lk = (tid & 3) << 2;
  const int bn = blockIdx.y * TN;
  const int p0 = bm + lrow;
  const int ar = (p0 < cnt) ? p0 : 0;
  float acc[4][4] = {};
  for (int k0 = 0; k0 < H; k0 += KT) {
    {
      float4 v = *reinterpret_cast<const float4*>(tb + (size_t)ar * H + k0 + lk);
      As[lk + 0][lrow] = v.x; As[lk + 1][lrow] = v.y;
      As[lk + 2][lrow] = v.z; As[lk + 3][lrow] = v.w;
    }
    {
      float4 v = *reinterpret_cast<const float4*>(Uh + (size_t)(bn + lrow) * H + k0 + lk);
      Bs[lk + 0][lrow] = v.x; Bs[lk + 1][lrow] = v.y;
      Bs[lk + 2][lrow] = v.z; Bs[lk + 3][lrow] = v.w;
    }
    __syncthreads();
#pragma unroll
    for (int k = 0; k < KT; ++k) {
      float4 av = *reinterpret_cast<const float4*>(&As[k][ty << 2]);
      float4 bv = *reinterpret_cast<const float4*>(&Bs[k][tx << 2]);
      fma16(acc, av, bv);
    }
    __syncthreads();
  }
#pragma unroll
  for (int i = 0; i < 4; ++i) {
    int p = bm + (ty << 2) + i;
    if (p >= cnt) break;
    int g = rl[p];
    int col = bn + (tx << 2);
    float4 xhv = *reinterpret_cast<const float4*>(xh + (size_t)g * H + col);
    float4 hsv = *reinterpret_cast<const float4*>(hs + (size_t)p * H + col);
    float4 zv  = *reinterpret_cast<const float4*>(zb + (size_t)p * H + col);
    float4 hv;
    float hh;
    hh = tanhf(xhv.x + acc[i][0]); hv.x = (1.0f - zv.x) * hsv.x + zv.x * hh;
    hh = tanhf(xhv.y + acc[i][1]); hv.y = (1.0f - zv.y) * hsv.y + zv.y * hh;
    hh = tanhf(xhv.z + acc[i][2]); hv.z = (1.0f - zv.z) * hsv.z + zv.z * hh;
    hh = tanhf(xhv.w + acc[i][3]); hv.w = (1.0f - zv.w) * hsv.w + zv.w * hh;
    *reinterpret_cast<float4*>(h + (size_t)g * H + col) = hv;
  }
}

// -------- decoder: out = h @ dec_w^T + dec_b  (C == 4) ---------------------
__global__ __launch_bounds__(256) void decoder(const float* __restrict__ h,
                                               const float* __restrict__ w,
                                               const float* __restrict__ b,
                                               float* __restrict__ out, int N,
                                               int H) {
  int wid = (blockIdx.x * blockDim.x + threadIdx.x) >> 6;  // one wave per row
  int lane = threadIdx.x & 63;
  if (wid >= N) return;
  float a0 = 0.f, a1 = 0.f, a2 = 0.f, a3 = 0.f;
  for (int k = lane; k < H; k += 64) {
    float hv = h[(size_t)wid * H + k];
    a0 = fmaf(hv, w[0 * H + k], a0);
    a1 = fmaf(hv, w[1 * H + k], a1);
    a2 = fmaf(hv, w[2 * H + k], a2);
    a3 = fmaf(hv, w[3 * H + k], a3);
  }
#pragma unroll
  for (int o = 32; o > 0; o >>= 1) {
    a0 += __shfl_down(a0, o);
    a1 += __shfl_down(a1, o);
    a2 += __shfl_down(a2, o);
    a3 += __shfl_down(a3, o);
  }
  if (lane == 0) {
    out[(size_t)wid * 4 + 0] = a0 + b[0];
    out[(size_t)wid * 4 + 1] = a1 + b[1];
    out[(size_t)wid * 4 + 2] = a2 + b[2];
    out[(size_t)wid * 4 + 3] = a3 + b[3];
  }
}

extern "C" void kernel_launch(void* const* d_in, const int* in_sizes, int n_in,
                              void* d_out, int out_size, void* d_ws,
                              size_t ws_size, hipStream_t stream) {
  const float* x   = (const float*)d_in[0];
  const float* adj = (const float*)d_in[1];
  const int* level = (const int*)d_in[2];
  const float* E_w = (const float*)d_in[3];
  const float* Wr  = (const float*)d_in[4];
  const float* Wz  = (const float*)d_in[5];
  const float* Ur  = (const float*)d_in[6];
  const float* Uz  = (const float*)d_in[7];
  const float* Wh  = (const float*)d_in[8];
  const float* Uh  = (const float*)d_in[9];
  const float* dw  = (const float*)d_in[10];
  const float* db  = (const float*)d_in[11];

  const int N = in_sizes[2];          // 4096
  const int D = in_sizes[0] / N;      // 5000
  const int H = in_sizes[3] / D;      // 512
  const int L = 8;                    // n_levels (device scalar; fixed)

  const size_t NH = (size_t)N * H;
  float* x_hat = (float*)d_ws;
  float* xr = x_hat + NH;
  float* xz = xr + NH;
  float* xh = xz + NH;
  float* h  = xh + NH;
  float* hs = h + NH;
  float* tb = hs + NH;
  float* zb = tb + NH;
  int* counts = (int*)(zb + NH);
  int* rowsl = counts + L;
  size_t need = (8 * NH + L) * sizeof(float) + (size_t)L * N * sizeof(int);
  if (ws_size < need) return;  // fail loudly (output stays zero)

  hipMemsetAsync(counts, 0, L * sizeof(int), stream);
  hipMemsetAsync(h, 0, NH * sizeof(float), stream);
  build_lists<<<(N + 255) / 256, 256, 0, stream>>>(level, counts, rowsl, N);

  // x_hat = x @ E_w^T
  gemm_tn3<<<dim3(N / TM, H / TN, 1), 256, 0, stream>>>(
      x, E_w, E_w, E_w, x_hat, x_hat, x_hat, N, H, D);
  // xr/xz/xh = x_hat @ {Wr,Wz,Wh}^T
  gemm_tn3<<<dim3(N / TM, H / TN, 3), 256, 0, stream>>>(
      x_hat, Wr, Wz, Wh, xr, xz, xh, N, H, H);

  const int gmx = (N + TM - 1) / TM;  // covers any level count
  for (int j = L - 1; j >= 0; --j) {
    agg_gather<<<dim3(gmx, H / TN), 256, 0, stream>>>(adj, h, rowsl, counts, j,
                                                      N, H, hs);
    gates_rz<<<dim3(gmx, H / TN), 256, 0, stream>>>(hs, Ur, Uz, xr, xz, rowsl,
                                                    counts, j, N, H, tb, zb);
    gates_h<<<dim3(gmx, H / TN), 256, 0, stream>>>(tb, Uh, xh, hs, zb, rowsl,
                                                   counts, j, N, H, h);
  }
  decoder<<<dim3(N / 4), 256, 0, stream>>>(h, dw, db, (float*)d_out, N, H);
}

// Round 2
// 1330.083 us; speedup vs baseline: 2.5860x; 2.5860x over previous
//
#include <hip/hip_runtime.h>
#include <math.h>

// Round 1: fp32 throughout (numerics: chaotic net, bf16 too risky vs 2%-of-absmax
// threshold; fp32 baseline absmax 4.4e12 vs thr 1.55e13).
// Changes vs round 0:
//  - 128x64-tile / 8x4-per-thread fp32 GEMM (2 FLOP/LDS-byte -> VALU-bound, was
//    33% LDS-BW-capped) for x_hat (split-K=4, partials in hs/tb/zb + combine)
//    and xr/xz/xh (z-batched).
//  - LDS pads (132/68) -> staging bank conflicts 4-way -> 2-way (free).
//  - agg: split-K=5 (grid 480 blocks, was 64 active), partials in dead x_hat,
//    reduce kernel; level 7 agg skipped (h==0).
//  - gates: exact grids (PMAX=768), padded LDS.

#define PMAX 768   // max rows per level (cnt ~ Binom(4096,1/8): 512 +- 21, 768 = +12 sigma)
#define AKS 5      // agg split-K factor
#define AKC 832    // agg K-chunk (52*16; last chunk 768 = 48*16)
#define XKS 4      // x_hat split-K factor

__device__ __forceinline__ float sigf(float x) { return 1.0f / (1.0f + __expf(-x)); }

// guarded float4 load (never dereferences OOB elements)
__device__ __forceinline__ float4 ld4g(const float* p, int kidx, int K) {
  float4 v;
  v.x = (kidx + 0 < K) ? p[0] : 0.0f;
  v.y = (kidx + 1 < K) ? p[1] : 0.0f;
  v.z = (kidx + 2 < K) ? p[2] : 0.0f;
  v.w = (kidx + 3 < K) ? p[3] : 0.0f;
  return v;
}

// -------- build per-level row lists --------
__global__ __launch_bounds__(256) void build_lists(const int* __restrict__ level,
                                                   int* __restrict__ counts,
                                                   int* __restrict__ rows, int N) {
  int i = blockIdx.x * blockDim.x + threadIdx.x;
  if (i < N) {
    int j = level[i];
    int p = atomicAdd(&counts[j], 1);
    rows[(size_t)j * N + p] = i;
  }
}

// -------- core: C = A @ B^T over K-range [kb,ke). 128x64 tile, 256 thr, 8x4 --
__device__ __forceinline__ void gemm128x64(const float* __restrict__ A, int lda,
                                           const float* __restrict__ B, int ldb,
                                           float* __restrict__ C, int ldc,
                                           int kb, int ke, int bm, int bn) {
  __shared__ float As[16][132];  // pad 132: 16B-aligned f4 reads, 2-way writes
  __shared__ float Bs[16][68];
  const int tid = threadIdx.x;
  const int arow = tid >> 1, akq = (tid & 1) << 3;   // A loader: 2 f4 along K
  const int brow = tid >> 2, bkq = (tid & 3) << 2;   // B loader: 1 f4 along K
  const int ty = tid >> 4, tx = tid & 15;
  const int m0 = ty << 3, n0 = tx << 2;
  float acc[8][4] = {};
  const float* ap = A + (size_t)(bm + arow) * lda + kb + akq;
  const float* bp = B + (size_t)(bn + brow) * ldb + kb + bkq;
  for (int k0 = kb; k0 < ke; k0 += 16) {
    float4 a0, a1, b0;
    if (k0 + 16 <= ke) {
      a0 = *reinterpret_cast<const float4*>(ap);
      a1 = *reinterpret_cast<const float4*>(ap + 4);
      b0 = *reinterpret_cast<const float4*>(bp);
    } else {  // K tail
      a0 = ld4g(ap, k0 + akq, ke);
      a1 = ld4g(ap + 4, k0 + akq + 4, ke);
      b0 = ld4g(bp, k0 + bkq, ke);
    }
    ap += 16; bp += 16;
    __syncthreads();
    As[akq + 0][arow] = a0.x; As[akq + 1][arow] = a0.y;
    As[akq + 2][arow] = a0.z; As[akq + 3][arow] = a0.w;
    As[akq + 4][arow] = a1.x; As[akq + 5][arow] = a1.y;
    As[akq + 6][arow] = a1.z; As[akq + 7][arow] = a1.w;
    Bs[bkq + 0][brow] = b0.x; Bs[bkq + 1][brow] = b0.y;
    Bs[bkq + 2][brow] = b0.z; Bs[bkq + 3][brow] = b0.w;
    __syncthreads();
#pragma unroll
    for (int k = 0; k < 16; ++k) {
      float4 av0 = *reinterpret_cast<const float4*>(&As[k][m0]);
      float4 av1 = *reinterpret_cast<const float4*>(&As[k][m0 + 4]);
      float4 bv  = *reinterpret_cast<const float4*>(&Bs[k][n0]);
      float a[8] = {av0.x, av0.y, av0.z, av0.w, av1.x, av1.y, av1.z, av1.w};
      float b[4] = {bv.x, bv.y, bv.z, bv.w};
#pragma unroll
      for (int i = 0; i < 8; ++i)
#pragma unroll
        for (int j = 0; j < 4; ++j)
          acc[i][j] = fmaf(a[i], b[j], acc[i][j]);
    }
  }
  float* cp = C + (size_t)(bm + m0) * ldc + bn + n0;
#pragma unroll
  for (int i = 0; i < 8; ++i)
    *reinterpret_cast<float4*>(cp + (size_t)i * ldc) =
        make_float4(acc[i][0], acc[i][1], acc[i][2], acc[i][3]);
}

// x_hat split-K: grid.z picks K-chunk and partial output buffer
__global__ __launch_bounds__(256) void gemm_xhat(
    const float* __restrict__ A, const float* __restrict__ B,
    float* __restrict__ C0, float* __restrict__ C1, float* __restrict__ C2,
    float* __restrict__ C3, int lda, int K, int kc, int ldc) {
  float* C = (blockIdx.z == 0) ? C0
           : (blockIdx.z == 1) ? C1
           : (blockIdx.z == 2) ? C2 : C3;
  int kb = blockIdx.z * kc;
  int ke = min(K, kb + kc);
  gemm128x64(A, lda, B, lda, C, ldc, kb, ke, blockIdx.y * 128, blockIdx.x * 64);
}

// xr/xz/xh batched: grid.z picks (B,C)
__global__ __launch_bounds__(256) void gemm_w3(
    const float* __restrict__ A, const float* __restrict__ B0,
    const float* __restrict__ B1, const float* __restrict__ B2,
    float* __restrict__ C0, float* __restrict__ C1, float* __restrict__ C2,
    int K) {
  const float* B = (blockIdx.z == 0) ? B0 : (blockIdx.z == 1) ? B1 : B2;
  float* C = (blockIdx.z == 0) ? C0 : (blockIdx.z == 1) ? C1 : C2;
  gemm128x64(A, K, B, K, C, K, 0, K, blockIdx.y * 128, blockIdx.x * 64);
}

// x_hat = p0 + p1 + p2 + p3 (in place on p0)
__global__ __launch_bounds__(256) void combine4(float* __restrict__ c,
                                                const float* __restrict__ p1,
                                                const float* __restrict__ p2,
                                                const float* __restrict__ p3,
                                                int n4) {
  int i = blockIdx.x * 256 + threadIdx.x;
  if (i < n4) {
    float4 a = reinterpret_cast<float4*>(c)[i];
    float4 b = reinterpret_cast<const float4*>(p1)[i];
    float4 d = reinterpret_cast<const float4*>(p2)[i];
    float4 e = reinterpret_cast<const float4*>(p3)[i];
    a.x += b.x + d.x + e.x;
    a.y += b.y + d.y + e.y;
    a.z += b.z + d.z + e.z;
    a.w += b.w + d.w + e.w;
    reinterpret_cast<float4*>(c)[i] = a;
  }
}

// -------- agg split-K: part[z][p][:] = adj[rows[p], kb:ke) @ h[kb:ke, :] ----
__global__ __launch_bounds__(256) void agg_split(
    const float* __restrict__ adj, const float* __restrict__ h,
    const int* __restrict__ rows, const int* __restrict__ counts, int lvl,
    int N, int H, float* __restrict__ part) {
  const int cnt = min(counts[lvl], PMAX);
  const int bm = blockIdx.x * 64;
  if (bm >= cnt) return;
  const int z = blockIdx.z;
  const int kb = z * AKC;
  const int ke = min(N, kb + AKC);  // chunks are multiples of 16
  const int* rl = rows + (size_t)lvl * N;
  __shared__ float As[16][68];
  __shared__ float Bs[16][64];
  const int tid = threadIdx.x;
  const int lrow = tid >> 2, lk = (tid & 3) << 2;   // A loader (transpose)
  const int bkr = tid >> 4, bn4 = (tid & 15) << 2;  // B loader (direct)
  const int ty = tid >> 4, tx = tid & 15;
  const int m0 = ty << 2, n0 = tx << 2;
  const int bn = blockIdx.y * 64;
  const int p0 = bm + lrow;
  const int arow = rl[(p0 < cnt) ? p0 : (cnt - 1)];  // clamp (never stored)
  float acc[4][4] = {};
  const float* ap = adj + (size_t)arow * N + kb + lk;
  const float* bp = h + (size_t)(kb + bkr) * H + bn + bn4;
  for (int k0 = kb; k0 < ke; k0 += 16) {
    float4 va = *reinterpret_cast<const float4*>(ap); ap += 16;
    float4 vb = *reinterpret_cast<const float4*>(bp); bp += (size_t)16 * H;
    __syncthreads();
    As[lk + 0][lrow] = va.x; As[lk + 1][lrow] = va.y;
    As[lk + 2][lrow] = va.z; As[lk + 3][lrow] = va.w;
    *reinterpret_cast<float4*>(&Bs[bkr][bn4]) = vb;
    __syncthreads();
#pragma unroll
    for (int k = 0; k < 16; ++k) {
      float4 av = *reinterpret_cast<const float4*>(&As[k][m0]);
      float4 bv = *reinterpret_cast<const float4*>(&Bs[k][n0]);
      float a[4] = {av.x, av.y, av.z, av.w};
      float b[4] = {bv.x, bv.y, bv.z, bv.w};
#pragma unroll
      for (int i = 0; i < 4; ++i)
#pragma unroll
        for (int j = 0; j < 4; ++j)
          acc[i][j] = fmaf(a[i], b[j], acc[i][j]);
    }
  }
  float* cp = part + (size_t)z * PMAX * H;
#pragma unroll
  for (int i = 0; i < 4; ++i) {
    int p = bm + m0 + i;
    if (p >= cnt) break;
    *reinterpret_cast<float4*>(cp + (size_t)p * H + bn + n0) =
        make_float4(acc[i][0], acc[i][1], acc[i][2], acc[i][3]);
  }
}

// hs[p,:] = sum_z part[z][p][:]   (H == 512 assumed: 128 f4 per row)
__global__ __launch_bounds__(256) void agg_reduce(const float* __restrict__ part,
                                                  const int* __restrict__ counts,
                                                  int lvl, int H,
                                                  float* __restrict__ hs) {
  const int cnt = min(counts[lvl], PMAX);
  int p = blockIdx.x * 2 + (threadIdx.x >> 7);
  int c4 = threadIdx.x & 127;
  if (p >= cnt) return;
  const size_t zs4 = (size_t)PMAX * H / 4;
  const float4* q = reinterpret_cast<const float4*>(part) + (size_t)p * (H / 4) + c4;
  float4 s = q[0];
#pragma unroll
  for (int z = 1; z < AKS; ++z) {
    float4 t = q[z * zs4];
    s.x += t.x; s.y += t.y; s.z += t.z; s.w += t.w;
  }
  reinterpret_cast<float4*>(hs + (size_t)p * H)[c4] = s;
}

// -------- r,z gates: tb = hs*sig(xr+hs@Ur^T), zb = sig(xz+hs@Uz^T) ----------
__global__ __launch_bounds__(256) void gates_rz(
    const float* __restrict__ hs, const float* __restrict__ Ur,
    const float* __restrict__ Uz, const float* __restrict__ xr,
    const float* __restrict__ xz, const int* __restrict__ rows,
    const int* __restrict__ counts, int lvl, int N, int H,
    float* __restrict__ tb, float* __restrict__ zb) {
  const int cnt = min(counts[lvl], PMAX);
  const int bm = blockIdx.x * 64;
  if (bm >= cnt) return;
  const int* rl = rows + (size_t)lvl * N;
  __shared__ float As[16][68];
  __shared__ float Br[16][68];
  __shared__ float Bz[16][68];
  const int tid = threadIdx.x;
  const int lrow = tid >> 2, lk = (tid & 3) << 2;
  const int ty = tid >> 4, tx = tid & 15;
  const int m0 = ty << 2, n0 = tx << 2;
  const int bn = blockIdx.y * 64;
  float accR[4][4] = {};
  float accZ[4][4] = {};
  const float* ap = hs + (size_t)(bm + lrow) * H + lk;  // rows < PMAX: valid mem
  const float* rp = Ur + (size_t)(bn + lrow) * H + lk;
  const float* zp = Uz + (size_t)(bn + lrow) * H + lk;
  for (int k0 = 0; k0 < H; k0 += 16) {
    float4 va = *reinterpret_cast<const float4*>(ap); ap += 16;
    float4 vr = *reinterpret_cast<const float4*>(rp); rp += 16;
    float4 vz = *reinterpret_cast<const float4*>(zp); zp += 16;
    __syncthreads();
    As[lk + 0][lrow] = va.x; As[lk + 1][lrow] = va.y;
    As[lk + 2][lrow] = va.z; As[lk + 3][lrow] = va.w;
    Br[lk + 0][lrow] = vr.x; Br[lk + 1][lrow] = vr.y;
    Br[lk + 2][lrow] = vr.z; Br[lk + 3][lrow] = vr.w;
    Bz[lk + 0][lrow] = vz.x; Bz[lk + 1][lrow] = vz.y;
    Bz[lk + 2][lrow] = vz.z; Bz[lk + 3][lrow] = vz.w;
    __syncthreads();
#pragma unroll
    for (int k = 0; k < 16; ++k) {
      float4 av = *reinterpret_cast<const float4*>(&As[k][m0]);
      float4 br = *reinterpret_cast<const float4*>(&Br[k][n0]);
      float4 bz = *reinterpret_cast<const float4*>(&Bz[k][n0]);
      float a[4] = {av.x, av.y, av.z, av.w};
      float r[4] = {br.x, br.y, br.z, br.w};
      float z[4] = {bz.x, bz.y, bz.z, bz.w};
#pragma unroll
      for (int i = 0; i < 4; ++i)
#pragma unroll
        for (int j = 0; j < 4; ++j) {
          accR[i][j] = fmaf(a[i], r[j], accR[i][j]);
          accZ[i][j] = fmaf(a[i], z[j], accZ[i][j]);
        }
    }
  }
#pragma unroll
  for (int i = 0; i < 4; ++i) {
    int p = bm + m0 + i;
    if (p >= cnt) break;
    int g = rl[p];
    int col = bn + n0;
    float4 xrv = *reinterpret_cast<const float4*>(xr + (size_t)g * H + col);
    float4 xzv = *reinterpret_cast<const float4*>(xz + (size_t)g * H + col);
    float4 hsv = *reinterpret_cast<const float4*>(hs + (size_t)p * H + col);
    float4 tv, zv;
    tv.x = hsv.x * sigf(xrv.x + accR[i][0]);
    tv.y = hsv.y * sigf(xrv.y + accR[i][1]);
    tv.z = hsv.z * sigf(xrv.z + accR[i][2]);
    tv.w = hsv.w * sigf(xrv.w + accR[i][3]);
    zv.x = sigf(xzv.x + accZ[i][0]);
    zv.y = sigf(xzv.y + accZ[i][1]);
    zv.z = sigf(xzv.z + accZ[i][2]);
    zv.w = sigf(xzv.w + accZ[i][3]);
    *reinterpret_cast<float4*>(tb + (size_t)p * H + col) = tv;
    *reinterpret_cast<float4*>(zb + (size_t)p * H + col) = zv;
  }
}

// -------- h-hat + state update: h[g,:] = (1-z)*hs + z*tanh(xh + tb@Uh^T) ----
__global__ __launch_bounds__(256) void gates_h(
    const float* __restrict__ tb, const float* __restrict__ Uh,
    const float* __restrict__ xh, const float* __restrict__ hs,
    const float* __restrict__ zb, const int* __restrict__ rows,
    const int* __restrict__ counts, int lvl, int N, int H,
    float* __restrict__ h) {
  const int cnt = min(counts[lvl], PMAX);
  const int bm = blockIdx.x * 64;
  if (bm >= cnt) return;
  const int* rl = rows + (size_t)lvl * N;
  __shared__ float As[16][68];
  __shared__ float Bs[16][68];
  const int tid = threadIdx.x;
  const int lrow = tid >> 2, lk = (tid & 3) << 2;
  const int ty = tid >> 4, tx = tid & 15;
  const int m0 = ty << 2, n0 = tx << 2;
  const int bn = blockIdx.y * 64;
  float acc[4][4] = {};
  const float* ap = tb + (size_t)(bm + lrow) * H + lk;
  const float* up = Uh + (size_t)(bn + lrow) * H + lk;
  for (int k0 = 0; k0 < H; k0 += 16) {
    float4 va = *reinterpret_cast<const float4*>(ap); ap += 16;
    float4 vu = *reinterpret_cast<const float4*>(up); up += 16;
    __syncthreads();
    As[lk + 0][lrow] = va.x; As[lk + 1][lrow] = va.y;
    As[lk + 2][lrow] = va.z; As[lk + 3][lrow] = va.w;
    Bs[lk + 0][lrow] = vu.x; Bs[lk + 1][lrow] = vu.y;
    Bs[lk + 2][lrow] = vu.z; Bs[lk + 3][lrow] = vu.w;
    __syncthreads();
#pragma unroll
    for (int k = 0; k < 16; ++k) {
      float4 av = *reinterpret_cast<const float4*>(&As[k][m0]);
      float4 bv = *reinterpret_cast<const float4*>(&Bs[k][n0]);
      float a[4] = {av.x, av.y, av.z, av.w};
      float b[4] = {bv.x, bv.y, bv.z, bv.w};
#pragma unroll
      for (int i = 0; i < 4; ++i)
#pragma unroll
        for (int j = 0; j < 4; ++j)
          acc[i][j] = fmaf(a[i], b[j], acc[i][j]);
    }
  }
#pragma unroll
  for (int i = 0; i < 4; ++i) {
    int p = bm + m0 + i;
    if (p >= cnt) break;
    int g = rl[p];
    int col = bn + n0;
    float4 xhv = *reinterpret_cast<const float4*>(xh + (size_t)g * H + col);
    float4 hsv = *reinterpret_cast<const float4*>(hs + (size_t)p * H + col);
    float4 zv  = *reinterpret_cast<const float4*>(zb + (size_t)p * H + col);
    float4 hv;
    float hh;
    hh = tanhf(xhv.x + acc[i][0]); hv.x = (1.0f - zv.x) * hsv.x + zv.x * hh;
    hh = tanhf(xhv.y + acc[i][1]); hv.y = (1.0f - zv.y) * hsv.y + zv.y * hh;
    hh = tanhf(xhv.z + acc[i][2]); hv.z = (1.0f - zv.z) * hsv.z + zv.z * hh;
    hh = tanhf(xhv.w + acc[i][3]); hv.w = (1.0f - zv.w) * hsv.w + zv.w * hh;
    *reinterpret_cast<float4*>(h + (size_t)g * H + col) = hv;
  }
}

// -------- decoder: out = h @ dec_w^T + dec_b  (C == 4) ---------------------
__global__ __launch_bounds__(256) void decoder(const float* __restrict__ h,
                                               const float* __restrict__ w,
                                               const float* __restrict__ b,
                                               float* __restrict__ out, int N,
                                               int H) {
  int wid = (blockIdx.x * blockDim.x + threadIdx.x) >> 6;
  int lane = threadIdx.x & 63;
  if (wid >= N) return;
  float a0 = 0.f, a1 = 0.f, a2 = 0.f, a3 = 0.f;
  for (int k = lane; k < H; k += 64) {
    float hv = h[(size_t)wid * H + k];
    a0 = fmaf(hv, w[0 * H + k], a0);
    a1 = fmaf(hv, w[1 * H + k], a1);
    a2 = fmaf(hv, w[2 * H + k], a2);
    a3 = fmaf(hv, w[3 * H + k], a3);
  }
#pragma unroll
  for (int o = 32; o > 0; o >>= 1) {
    a0 += __shfl_down(a0, o);
    a1 += __shfl_down(a1, o);
    a2 += __shfl_down(a2, o);
    a3 += __shfl_down(a3, o);
  }
  if (lane == 0) {
    out[(size_t)wid * 4 + 0] = a0 + b[0];
    out[(size_t)wid * 4 + 1] = a1 + b[1];
    out[(size_t)wid * 4 + 2] = a2 + b[2];
    out[(size_t)wid * 4 + 3] = a3 + b[3];
  }
}

extern "C" void kernel_launch(void* const* d_in, const int* in_sizes, int n_in,
                              void* d_out, int out_size, void* d_ws,
                              size_t ws_size, hipStream_t stream) {
  const float* x   = (const float*)d_in[0];
  const float* adj = (const float*)d_in[1];
  const int* level = (const int*)d_in[2];
  const float* E_w = (const float*)d_in[3];
  const float* Wr  = (const float*)d_in[4];
  const float* Wz  = (const float*)d_in[5];
  const float* Ur  = (const float*)d_in[6];
  const float* Uz  = (const float*)d_in[7];
  const float* Wh  = (const float*)d_in[8];
  const float* Uh  = (const float*)d_in[9];
  const float* dw  = (const float*)d_in[10];
  const float* db  = (const float*)d_in[11];

  const int N = in_sizes[2];      // 4096
  const int D = in_sizes[0] / N;  // 5000
  const int H = in_sizes[3] / D;  // 512
  const int L = 8;

  const size_t NH = (size_t)N * H;
  float* x_hat = (float*)d_ws;    // also: x_hat-GEMM partial z=0; agg partial arena
  float* xr = x_hat + NH;
  float* xz = xr + NH;
  float* xh = xz + NH;
  float* h  = xh + NH;
  float* hs = h + NH;             // also: x_hat-GEMM partial z=1
  float* tb = hs + NH;            // also: partial z=2
  float* zb = tb + NH;            // also: partial z=3
  int* counts = (int*)(zb + NH);
  int* rowsl = counts + L;
  size_t need = (8 * NH + L) * sizeof(float) + (size_t)L * N * sizeof(int);
  if (ws_size < need) return;

  hipMemsetAsync(counts, 0, L * sizeof(int), stream);
  hipMemsetAsync(h, 0, NH * sizeof(float), stream);
  build_lists<<<(N + 255) / 256, 256, 0, stream>>>(level, counts, rowsl, N);

  // x_hat = x @ E_w^T, split-K=4, partials -> x_hat,hs,tb,zb
  const int kc = (D + XKS - 1) / XKS;  // 1250
  gemm_xhat<<<dim3(H / 64, N / 128, XKS), 256, 0, stream>>>(
      x, E_w, x_hat, hs, tb, zb, D, D, kc, H);
  combine4<<<(int)(NH / 4 + 255) / 256, 256, 0, stream>>>(x_hat, hs, tb, zb,
                                                          (int)(NH / 4));
  // xr/xz/xh = x_hat @ {Wr,Wz,Wh}^T
  gemm_w3<<<dim3(H / 64, N / 128, 3), 256, 0, stream>>>(x_hat, Wr, Wz, Wh, xr,
                                                        xz, xh, H);
  // hs head must be zero for level L-1 (h == 0 there; agg skipped)
  hipMemsetAsync(hs, 0, (size_t)PMAX * H * sizeof(float), stream);

  const dim3 ggrid(PMAX / 64, H / 64);
  for (int j = L - 1; j >= 0; --j) {
    if (j != L - 1) {
      agg_split<<<dim3(PMAX / 64, H / 64, AKS), 256, 0, stream>>>(
          adj, h, rowsl, counts, j, N, H, x_hat);
      agg_reduce<<<PMAX / 2, 256, 0, stream>>>(x_hat, counts, j, H, hs);
    }
    gates_rz<<<ggrid, 256, 0, stream>>>(hs, Ur, Uz, xr, xz, rowsl, counts, j, N,
                                        H, tb, zb);
    gates_h<<<ggrid, 256, 0, stream>>>(tb, Uh, xh, hs, zb, rowsl, counts, j, N,
                                       H, h);
  }
  decoder<<<dim3(N / 4), 256, 0, stream>>>(h, dw, db, (float*)d_out, N, H);
}

// Round 4
// 1217.836 us; speedup vs baseline: 2.8244x; 1.0922x over previous
//
#include <hip/hip_runtime.h>
#include <math.h>

// Round 3: "6xBF16" fp32-emulation on MFMA.
// Each fp32 operand is split (by mantissa truncation, exact residuals) into
// hi+mid+lo bf16 planes; GEMM accumulates 6 MFMA products
// (hh, hm, mh, hl, lh, mm) in fp32 -> representation error ~2^-24 = fp32-class.
// Round-2 evidence: plain bf16 (eps 4e-3) -> 1.86e14; fp32 -> 4.4e12; power-law
// fit says 2-term split (1e-5) ~2.5e13 > 1.56e13 threshold, 3-term is safe.
//  - 16x16x32 bf16 MFMA, 64x128 tile (64x64 for gates), 4 waves 2x2.
//  - 3-plane LDS tiles, stride 40 ushorts (16B-aligned b128, ~2-way banks).
//  - Pre-split to planes: U weights, x_hat, h(T), hs, tb (written in epilogues).
//  - On-the-fly split in staging: x, E_w, W (streamed), adj (A-side, hidden).
//  - States fp32: xr/xz/xh, hsf, zb. Output path identical to round 1.

#define NNODE 4096
#define DD 5000
#define HH 512
#define LL 8
#define PMAX 768          // max rows/level (Binom(4096,1/8)=512+-21; +12 sigma)
#define AKS 4             // agg split-K chunks
#define AKC 1024          // NNODE/AKS
#define STR 40            // LDS row stride (ushorts)
#define NHt 2097152       // NNODE*HH

typedef __attribute__((ext_vector_type(8))) short short8v;
typedef __attribute__((ext_vector_type(4))) float float4v;

union fu { float f; unsigned u; };

__device__ __forceinline__ float sigf(float x) { return 1.0f / (1.0f + __expf(-x)); }
__device__ __forceinline__ float bf2f(ushort b) { fu v; v.u = ((unsigned)b) << 16; return v.f; }

// truncation split of a pair into packed u32 per plane (elem0=low16, elem1=high16)
__device__ __forceinline__ void splitpair(float a, float b, unsigned& hi,
                                          unsigned& mi, unsigned& lo) {
  const unsigned M = 0xFFFF0000u;
  fu A, B; A.f = a; B.f = b;
  hi = (A.u >> 16) | (B.u & M);
  fu Ah, Bh; Ah.u = A.u & M; Bh.u = B.u & M;
  float ra = a - Ah.f, rb = b - Bh.f;
  fu A1, B1; A1.f = ra; B1.f = rb;
  mi = (A1.u >> 16) | (B1.u & M);
  fu A1h, B1h; A1h.u = A1.u & M; B1h.u = B1.u & M;
  float ra2 = ra - A1h.f, rb2 = rb - B1h.f;
  fu A2, B2; A2.f = ra2; B2.f = rb2;
  lo = (A2.u >> 16) | (B2.u & M);
}

__device__ __forceinline__ void split8(const float* v, uint4& h, uint4& m, uint4& l) {
  splitpair(v[0], v[1], h.x, m.x, l.x);
  splitpair(v[2], v[3], h.y, m.y, l.y);
  splitpair(v[4], v[5], h.z, m.z, l.z);
  splitpair(v[6], v[7], h.w, m.w, l.w);
}

__device__ __forceinline__ void split1(float x, ushort& h, ushort& m, ushort& l) {
  const unsigned M = 0xFFFF0000u;
  fu a; a.f = x; h = (ushort)(a.u >> 16);
  fu ah; ah.u = a.u & M; float r = x - ah.f;
  fu b; b.f = r; m = (ushort)(b.u >> 16);
  fu bh; bh.u = b.u & M; float r2 = r - bh.f;
  fu c; c.f = r2; l = (ushort)(c.u >> 16);
}

// 6-product MFMA accumulate from 3-plane LDS tiles.
// A tile: 64 rows; B tile: bRows rows (template NB = B frags per wave).
template <int NB>
__device__ __forceinline__ void mfma6(const ushort* As, const ushort* Bs, int bRows,
                                      int wm, int wn, int lr, int lg8,
                                      float4v (*acc)[NB]) {
  short8v a[2][3];
#pragma unroll
  for (int im = 0; im < 2; ++im)
#pragma unroll
    for (int p = 0; p < 3; ++p)
      a[im][p] = *reinterpret_cast<const short8v*>(
          &As[(p * 64 + wm + 16 * im + lr) * STR + lg8]);
  short8v b[NB][3];
#pragma unroll
  for (int in = 0; in < NB; ++in)
#pragma unroll
    for (int p = 0; p < 3; ++p)
      b[in][p] = *reinterpret_cast<const short8v*>(
          &Bs[(p * bRows + wn + 16 * in + lr) * STR + lg8]);
#pragma unroll
  for (int im = 0; im < 2; ++im)
#pragma unroll
    for (int in = 0; in < NB; ++in) {
      float4v c = acc[im][in];
      c = __builtin_amdgcn_mfma_f32_16x16x32_bf16(a[im][0], b[in][0], c, 0, 0, 0);
      c = __builtin_amdgcn_mfma_f32_16x16x32_bf16(a[im][0], b[in][1], c, 0, 0, 0);
      c = __builtin_amdgcn_mfma_f32_16x16x32_bf16(a[im][1], b[in][0], c, 0, 0, 0);
      c = __builtin_amdgcn_mfma_f32_16x16x32_bf16(a[im][0], b[in][2], c, 0, 0, 0);
      c = __builtin_amdgcn_mfma_f32_16x16x32_bf16(a[im][2], b[in][0], c, 0, 0, 0);
      c = __builtin_amdgcn_mfma_f32_16x16x32_bf16(a[im][1], b[in][1], c, 0, 0, 0);
      acc[im][in] = c;
    }
}

// -------- per-level row lists ----------------------------------------------
__global__ __launch_bounds__(256) void build_lists(const int* __restrict__ level,
                                                   int* __restrict__ counts,
                                                   int* __restrict__ rows, int N) {
  int i = blockIdx.x * blockDim.x + threadIdx.x;
  if (i < N) {
    int j = level[i];
    int p = atomicAdd(&counts[j], 1);
    rows[(size_t)j * N + p] = i;
  }
}

// -------- pre-split Ur,Uz,Uh -> u3[mat][plane][HH*HH] ----------------------
__global__ __launch_bounds__(256) void cast_u3(const float* __restrict__ Ur,
                                               const float* __restrict__ Uz,
                                               const float* __restrict__ Uh,
                                               ushort* __restrict__ u3) {
  const float* src = (blockIdx.y == 0) ? Ur : (blockIdx.y == 1) ? Uz : Uh;
  int i = (blockIdx.x * 256 + threadIdx.x) * 8;
  float4 t0 = *reinterpret_cast<const float4*>(src + i);
  float4 t1 = *reinterpret_cast<const float4*>(src + i + 4);
  float v[8] = {t0.x, t0.y, t0.z, t0.w, t1.x, t1.y, t1.z, t1.w};
  uint4 h, m, l;
  split8(v, h, m, l);
  ushort* base = u3 + (size_t)blockIdx.y * 3 * HH * HH;
  *reinterpret_cast<uint4*>(base + i) = h;
  *reinterpret_cast<uint4*>(base + HH * HH + i) = m;
  *reinterpret_cast<uint4*>(base + 2 * HH * HH + i) = l;
}

// -------- x_hat = x @ E_w^T (fp32 in, on-the-fly split; 3-plane bf16 out) --
__global__ __launch_bounds__(256) void gemm_xhat6(const float* __restrict__ x,
                                                  const float* __restrict__ Ew,
                                                  ushort* __restrict__ xh3) {
  __shared__ ushort As[3 * 64 * STR];
  __shared__ ushort Bs[3 * 128 * STR];
  const int tid = threadIdx.x;
  const int bm = blockIdx.x * 64, bn = blockIdx.y * 128;
  const int wid = tid >> 6, lane = tid & 63;
  const int lr = lane & 15, lg = lane >> 4, lg8 = lg * 8;
  const int wm = (wid >> 1) * 32, wn = (wid & 1) * 64;
  const int ar = tid >> 2, akq = (tid & 3) * 8;
  const int br = tid >> 1, bkq = (tid & 1) * 16;
  const float* ap = x + (size_t)(bm + ar) * DD + akq;
  const float* bp = Ew + (size_t)(bn + br) * DD + bkq;
  float4v acc[2][4];
#pragma unroll
  for (int i = 0; i < 2; ++i)
#pragma unroll
    for (int j = 0; j < 4; ++j) acc[i][j] = (float4v){0.f, 0.f, 0.f, 0.f};
  uint4 ah, am, al, bh0, bm0, bl0, bh1, bm1, bl1;
  auto loadA = [&](int k0) {
    float v[8];
    if (k0 + 32 <= DD) {
      float4 t0 = *reinterpret_cast<const float4*>(ap);
      float4 t1 = *reinterpret_cast<const float4*>(ap + 4);
      v[0]=t0.x; v[1]=t0.y; v[2]=t0.z; v[3]=t0.w;
      v[4]=t1.x; v[5]=t1.y; v[6]=t1.z; v[7]=t1.w;
    } else {
#pragma unroll
      for (int i = 0; i < 8; ++i) v[i] = (k0 + akq + i < DD) ? ap[i] : 0.0f;
    }
    split8(v, ah, am, al);
    ap += 32;
  };
  auto loadB = [&](int k0) {
    float v[16];
    if (k0 + 32 <= DD) {
      float4 t0 = *reinterpret_cast<const float4*>(bp);
      float4 t1 = *reinterpret_cast<const float4*>(bp + 4);
      float4 t2 = *reinterpret_cast<const float4*>(bp + 8);
      float4 t3 = *reinterpret_cast<const float4*>(bp + 12);
      v[0]=t0.x; v[1]=t0.y; v[2]=t0.z; v[3]=t0.w;
      v[4]=t1.x; v[5]=t1.y; v[6]=t1.z; v[7]=t1.w;
      v[8]=t2.x; v[9]=t2.y; v[10]=t2.z; v[11]=t2.w;
      v[12]=t3.x; v[13]=t3.y; v[14]=t3.z; v[15]=t3.w;
    } else {
#pragma unroll
      for (int i = 0; i < 16; ++i) v[i] = (k0 + bkq + i < DD) ? bp[i] : 0.0f;
    }
    split8(v, bh0, bm0, bl0);
    split8(v + 8, bh1, bm1, bl1);
    bp += 32;
  };
  loadA(0); loadB(0);
  const int KT = 5024;  // DD rounded up to 32
  for (int k0 = 0; k0 < KT; k0 += 32) {
    __syncthreads();
    *reinterpret_cast<uint4*>(&As[(0 * 64 + ar) * STR + akq]) = ah;
    *reinterpret_cast<uint4*>(&As[(1 * 64 + ar) * STR + akq]) = am;
    *reinterpret_cast<uint4*>(&As[(2 * 64 + ar) * STR + akq]) = al;
    *reinterpret_cast<uint4*>(&Bs[(0 * 128 + br) * STR + bkq]) = bh0;
    *reinterpret_cast<uint4*>(&Bs[(0 * 128 + br) * STR + bkq + 8]) = bh1;
    *reinterpret_cast<uint4*>(&Bs[(1 * 128 + br) * STR + bkq]) = bm0;
    *reinterpret_cast<uint4*>(&Bs[(1 * 128 + br) * STR + bkq + 8]) = bm1;
    *reinterpret_cast<uint4*>(&Bs[(2 * 128 + br) * STR + bkq]) = bl0;
    *reinterpret_cast<uint4*>(&Bs[(2 * 128 + br) * STR + bkq + 8]) = bl1;
    __syncthreads();
    if (k0 + 32 < KT) { loadA(k0 + 32); loadB(k0 + 32); }
    mfma6<4>(As, Bs, 128, wm, wn, lr, lg8, acc);
  }
  ushort* hp = xh3;
  ushort* mp = xh3 + NHt;
  ushort* lp = xh3 + 2 * NHt;
#pragma unroll
  for (int im = 0; im < 2; ++im)
#pragma unroll
    for (int in = 0; in < 4; ++in)
#pragma unroll
      for (int r = 0; r < 4; ++r) {
        int row = bm + wm + im * 16 + lg * 4 + r;
        int col = bn + wn + in * 16 + lr;
        ushort h, m, l;
        split1(acc[im][in][r], h, m, l);
        size_t idx = (size_t)row * HH + col;
        hp[idx] = h; mp[idx] = m; lp[idx] = l;
      }
}

// -------- xr/xz/xh = x_hat @ {Wr,Wz,Wh}^T (A pre-split, B on-the-fly) ------
__global__ __launch_bounds__(256) void gemm_w36(const ushort* __restrict__ xh3,
                                                const float* __restrict__ W0,
                                                const float* __restrict__ W1,
                                                const float* __restrict__ W2,
                                                float* __restrict__ xrzh) {
  const float* W = (blockIdx.z == 0) ? W0 : (blockIdx.z == 1) ? W1 : W2;
  float* C = xrzh + (size_t)blockIdx.z * NHt;
  __shared__ ushort As[3 * 64 * STR];
  __shared__ ushort Bs[3 * 128 * STR];
  const int tid = threadIdx.x;
  const int bm = blockIdx.x * 64, bn = blockIdx.y * 128;
  const int wid = tid >> 6, lane = tid & 63;
  const int lr = lane & 15, lg = lane >> 4, lg8 = lg * 8;
  const int wm = (wid >> 1) * 32, wn = (wid & 1) * 64;
  const int ar = tid >> 2, akq = (tid & 3) * 8;
  const int br = tid >> 1, bkq = (tid & 1) * 16;
  const ushort* aph = xh3 + (size_t)(bm + ar) * HH + akq;
  const float* bp = W + (size_t)(bn + br) * HH + bkq;
  float4v acc[2][4];
#pragma unroll
  for (int i = 0; i < 2; ++i)
#pragma unroll
    for (int j = 0; j < 4; ++j) acc[i][j] = (float4v){0.f, 0.f, 0.f, 0.f};
  short8v a3[3];
  uint4 bh0, bm0, bl0, bh1, bm1, bl1;
  auto loadA = [&]() {
    a3[0] = *reinterpret_cast<const short8v*>(aph);
    a3[1] = *reinterpret_cast<const short8v*>(aph + NHt);
    a3[2] = *reinterpret_cast<const short8v*>(aph + 2 * NHt);
    aph += 32;
  };
  auto loadB = [&]() {
    float4 t0 = *reinterpret_cast<const float4*>(bp);
    float4 t1 = *reinterpret_cast<const float4*>(bp + 4);
    float4 t2 = *reinterpret_cast<const float4*>(bp + 8);
    float4 t3 = *reinterpret_cast<const float4*>(bp + 12);
    float v[16] = {t0.x,t0.y,t0.z,t0.w, t1.x,t1.y,t1.z,t1.w,
                   t2.x,t2.y,t2.z,t2.w, t3.x,t3.y,t3.z,t3.w};
    split8(v, bh0, bm0, bl0);
    split8(v + 8, bh1, bm1, bl1);
    bp += 32;
  };
  loadA(); loadB();
  for (int k0 = 0; k0 < HH; k0 += 32) {
    __syncthreads();
    *reinterpret_cast<short8v*>(&As[(0 * 64 + ar) * STR + akq]) = a3[0];
    *reinterpret_cast<short8v*>(&As[(1 * 64 + ar) * STR + akq]) = a3[1];
    *reinterpret_cast<short8v*>(&As[(2 * 64 + ar) * STR + akq]) = a3[2];
    *reinterpret_cast<uint4*>(&Bs[(0 * 128 + br) * STR + bkq]) = bh0;
    *reinterpret_cast<uint4*>(&Bs[(0 * 128 + br) * STR + bkq + 8]) = bh1;
    *reinterpret_cast<uint4*>(&Bs[(1 * 128 + br) * STR + bkq]) = bm0;
    *reinterpret_cast<uint4*>(&Bs[(1 * 128 + br) * STR + bkq + 8]) = bm1;
    *reinterpret_cast<uint4*>(&Bs[(2 * 128 + br) * STR + bkq]) = bl0;
    *reinterpret_cast<uint4*>(&Bs[(2 * 128 + br) * STR + bkq + 8]) = bl1;
    __syncthreads();
    if (k0 + 32 < HH) { loadA(); loadB(); }
    mfma6<4>(As, Bs, 128, wm, wn, lr, lg8, acc);
  }
#pragma unroll
  for (int im = 0; im < 2; ++im)
#pragma unroll
    for (int in = 0; in < 4; ++in)
#pragma unroll
      for (int r = 0; r < 4; ++r) {
        int row = bm + wm + im * 16 + lg * 4 + r;
        int col = bn + wn + in * 16 + lr;
        C[(size_t)row * HH + col] = acc[im][in][r];
      }
}

// -------- agg split-K: part[z][p][n] = adj[rows[p], kb:kb+AKC) @ h ---------
__global__ __launch_bounds__(256) void agg6(const float* __restrict__ adj,
                                            const ushort* __restrict__ hT3,
                                            const int* __restrict__ rows,
                                            const int* __restrict__ counts,
                                            int lvl, float* __restrict__ part) {
  const int cnt = min(counts[lvl], PMAX);
  const int bm = blockIdx.x * 64;
  if (bm >= cnt) return;
  const int* rl = rows + (size_t)lvl * NNODE;
  const int kb = blockIdx.z * AKC;
  const int bn = blockIdx.y * 128;
  __shared__ ushort As[3 * 64 * STR];
  __shared__ ushort Bs[3 * 128 * STR];
  const int tid = threadIdx.x;
  const int wid = tid >> 6, lane = tid & 63;
  const int lr = lane & 15, lg = lane >> 4, lg8 = lg * 8;
  const int wm = (wid >> 1) * 32, wn = (wid & 1) * 64;
  const int ar = tid >> 2, akq = (tid & 3) * 8;
  const int br = tid >> 1, bkq = (tid & 1) * 16;
  int p0 = bm + ar;
  if (p0 >= cnt) p0 = cnt - 1;  // clamp: duplicate row, never stored
  const float* ap = adj + (size_t)rl[p0] * NNODE + kb + akq;
  const ushort* bph = hT3 + (size_t)(bn + br) * NNODE + kb + bkq;
  float4v acc[2][4];
#pragma unroll
  for (int i = 0; i < 2; ++i)
#pragma unroll
    for (int j = 0; j < 4; ++j) acc[i][j] = (float4v){0.f, 0.f, 0.f, 0.f};
  uint4 ah, am, al;
  short8v b0[3], b1[3];
  auto loadA = [&]() {
    float4 t0 = *reinterpret_cast<const float4*>(ap);
    float4 t1 = *reinterpret_cast<const float4*>(ap + 4);
    float v[8] = {t0.x,t0.y,t0.z,t0.w, t1.x,t1.y,t1.z,t1.w};
    split8(v, ah, am, al);
    ap += 32;
  };
  auto loadB = [&]() {
#pragma unroll
    for (int p = 0; p < 3; ++p) {
      b0[p] = *reinterpret_cast<const short8v*>(bph + (size_t)p * NHt);
      b1[p] = *reinterpret_cast<const short8v*>(bph + (size_t)p * NHt + 8);
    }
    bph += 32;
  };
  loadA(); loadB();
  for (int k0 = 0; k0 < AKC; k0 += 32) {
    __syncthreads();
    *reinterpret_cast<uint4*>(&As[(0 * 64 + ar) * STR + akq]) = ah;
    *reinterpret_cast<uint4*>(&As[(1 * 64 + ar) * STR + akq]) = am;
    *reinterpret_cast<uint4*>(&As[(2 * 64 + ar) * STR + akq]) = al;
#pragma unroll
    for (int p = 0; p < 3; ++p) {
      *reinterpret_cast<short8v*>(&Bs[(p * 128 + br) * STR + bkq]) = b0[p];
      *reinterpret_cast<short8v*>(&Bs[(p * 128 + br) * STR + bkq + 8]) = b1[p];
    }
    __syncthreads();
    if (k0 + 32 < AKC) { loadA(); loadB(); }
    mfma6<4>(As, Bs, 128, wm, wn, lr, lg8, acc);
  }
  float* cp = part + (size_t)blockIdx.z * PMAX * HH;
#pragma unroll
  for (int im = 0; im < 2; ++im)
#pragma unroll
    for (int in = 0; in < 4; ++in)
#pragma unroll
      for (int r = 0; r < 4; ++r) {
        int p = bm + wm + im * 16 + lg * 4 + r;
        if (p < cnt)
          cp[(size_t)p * HH + bn + wn + in * 16 + lr] = acc[im][in][r];
      }
}

// -------- hs = sum_z part[z]; write fp32 + 3-plane split -------------------
__global__ __launch_bounds__(256) void agg_reduce6(const float* __restrict__ part,
                                                   float* __restrict__ hsf,
                                                   ushort* __restrict__ hs3) {
  int id = blockIdx.x * 256 + threadIdx.x;  // PMAX*HH/4 threads
  const int zs = PMAX * HH / 4;
  const float4* q = reinterpret_cast<const float4*>(part) + id;
  float4 s = q[0];
#pragma unroll
  for (int z = 1; z < AKS; ++z) {
    float4 t = q[(size_t)z * zs];
    s.x += t.x; s.y += t.y; s.z += t.z; s.w += t.w;
  }
  reinterpret_cast<float4*>(hsf)[id] = s;
  unsigned h0, m0, l0, h1, m1, l1;
  splitpair(s.x, s.y, h0, m0, l0);
  splitpair(s.z, s.w, h1, m1, l1);
  *reinterpret_cast<uint2*>(hs3 + (size_t)id * 4) = make_uint2(h0, h1);
  *reinterpret_cast<uint2*>(hs3 + PMAX * HH + (size_t)id * 4) = make_uint2(m0, m1);
  *reinterpret_cast<uint2*>(hs3 + 2 * PMAX * HH + (size_t)id * 4) = make_uint2(l0, l1);
}

// -------- r,z gates: tb3 = split(hs*sig(xr+hs@Ur^T)), zb = sig(xz+hs@Uz^T) -
__global__ __launch_bounds__(256) void gates_rz6(
    const ushort* __restrict__ hs3, const ushort* __restrict__ u3,
    const float* __restrict__ xr, const float* __restrict__ xz,
    const float* __restrict__ hsf, const int* __restrict__ rows,
    const int* __restrict__ counts, int lvl, ushort* __restrict__ tb3,
    float* __restrict__ zb) {
  const int cnt = min(counts[lvl], PMAX);
  const int bm = blockIdx.x * 64;
  if (bm >= cnt) return;
  const int* rl = rows + (size_t)lvl * NNODE;
  const int bn = blockIdx.y * 64;
  __shared__ ushort As[3 * 64 * STR];
  __shared__ ushort Br[3 * 64 * STR];
  __shared__ ushort Bz[3 * 64 * STR];
  const int tid = threadIdx.x;
  const int wid = tid >> 6, lane = tid & 63;
  const int lr = lane & 15, lg = lane >> 4, lg8 = lg * 8;
  const int wm = (wid >> 1) * 32, wn = (wid & 1) * 32;
  const int ar = tid >> 2, akq = (tid & 3) * 8;
  const ushort* aph = hs3 + (size_t)(bm + ar) * HH + akq;
  const ushort* rph = u3 + (size_t)0 * 3 * HH * HH + (size_t)(bn + ar) * HH + akq;
  const ushort* zph = u3 + (size_t)1 * 3 * HH * HH + (size_t)(bn + ar) * HH + akq;
  float4v accR[2][2], accZ[2][2];
#pragma unroll
  for (int i = 0; i < 2; ++i)
#pragma unroll
    for (int j = 0; j < 2; ++j) {
      accR[i][j] = (float4v){0.f, 0.f, 0.f, 0.f};
      accZ[i][j] = (float4v){0.f, 0.f, 0.f, 0.f};
    }
  short8v a3[3], r3[3], z3[3];
  auto loadAll = [&]() {
#pragma unroll
    for (int p = 0; p < 3; ++p) {
      a3[p] = *reinterpret_cast<const short8v*>(aph + (size_t)p * PMAX * HH);
      r3[p] = *reinterpret_cast<const short8v*>(rph + (size_t)p * HH * HH);
      z3[p] = *reinterpret_cast<const short8v*>(zph + (size_t)p * HH * HH);
    }
    aph += 32; rph += 32; zph += 32;
  };
  loadAll();
  for (int k0 = 0; k0 < HH; k0 += 32) {
    __syncthreads();
#pragma unroll
    for (int p = 0; p < 3; ++p) {
      *reinterpret_cast<short8v*>(&As[(p * 64 + ar) * STR + akq]) = a3[p];
      *reinterpret_cast<short8v*>(&Br[(p * 64 + ar) * STR + akq]) = r3[p];
      *reinterpret_cast<short8v*>(&Bz[(p * 64 + ar) * STR + akq]) = z3[p];
    }
    __syncthreads();
    if (k0 + 32 < HH) loadAll();
    mfma6<2>(As, Br, 64, wm, wn, lr, lg8, accR);
    mfma6<2>(As, Bz, 64, wm, wn, lr, lg8, accZ);
  }
  ushort* th = tb3;
  ushort* tm = tb3 + PMAX * HH;
  ushort* tl = tb3 + 2 * PMAX * HH;
#pragma unroll
  for (int im = 0; im < 2; ++im)
#pragma unroll
    for (int in = 0; in < 2; ++in)
#pragma unroll
      for (int r = 0; r < 4; ++r) {
        int p = bm + wm + im * 16 + lg * 4 + r;
        if (p < cnt) {
          int col = bn + wn + in * 16 + lr;
          int g = rl[p];
          float xrv = xr[(size_t)g * HH + col];
          float xzv = xz[(size_t)g * HH + col];
          float hsv = hsf[(size_t)p * HH + col];
          float rr = sigf(xrv + accR[im][in][r]);
          float zz = sigf(xzv + accZ[im][in][r]);
          ushort h, m, l;
          split1(hsv * rr, h, m, l);
          size_t idx = (size_t)p * HH + col;
          th[idx] = h; tm[idx] = m; tl[idx] = l;
          zb[idx] = zz;
        }
      }
}

// -------- h-hat + update: hT3[col][g] = split((1-z)hs + z*tanh(xh+tb@Uh^T)) -
__global__ __launch_bounds__(256) void gates_h6(
    const ushort* __restrict__ tb3, const ushort* __restrict__ u3,
    const float* __restrict__ xh, const float* __restrict__ hsf,
    const float* __restrict__ zb, const int* __restrict__ rows,
    const int* __restrict__ counts, int lvl, ushort* __restrict__ hT3) {
  const int cnt = min(counts[lvl], PMAX);
  const int bm = blockIdx.x * 64;
  if (bm >= cnt) return;
  const int* rl = rows + (size_t)lvl * NNODE;
  const int bn = blockIdx.y * 64;
  __shared__ ushort As[3 * 64 * STR];
  __shared__ ushort Bs[3 * 64 * STR];
  const int tid = threadIdx.x;
  const int wid = tid >> 6, lane = tid & 63;
  const int lr = lane & 15, lg = lane >> 4, lg8 = lg * 8;
  const int wm = (wid >> 1) * 32, wn = (wid & 1) * 32;
  const int ar = tid >> 2, akq = (tid & 3) * 8;
  const ushort* aph = tb3 + (size_t)(bm + ar) * HH + akq;
  const ushort* bph = u3 + (size_t)2 * 3 * HH * HH + (size_t)(bn + ar) * HH + akq;
  float4v acc[2][2];
#pragma unroll
  for (int i = 0; i < 2; ++i)
#pragma unroll
    for (int j = 0; j < 2; ++j) acc[i][j] = (float4v){0.f, 0.f, 0.f, 0.f};
  short8v a3[3], b3[3];
  auto loadAll = [&]() {
#pragma unroll
    for (int p = 0; p < 3; ++p) {
      a3[p] = *reinterpret_cast<const short8v*>(aph + (size_t)p * PMAX * HH);
      b3[p] = *reinterpret_cast<const short8v*>(bph + (size_t)p * HH * HH);
    }
    aph += 32; bph += 32;
  };
  loadAll();
  for (int k0 = 0; k0 < HH; k0 += 32) {
    __syncthreads();
#pragma unroll
    for (int p = 0; p < 3; ++p) {
      *reinterpret_cast<short8v*>(&As[(p * 64 + ar) * STR + akq]) = a3[p];
      *reinterpret_cast<short8v*>(&Bs[(p * 64 + ar) * STR + akq]) = b3[p];
    }
    __syncthreads();
    if (k0 + 32 < HH) loadAll();
    mfma6<2>(As, Bs, 64, wm, wn, lr, lg8, acc);
  }
  ushort* hp = hT3;
  ushort* mp = hT3 + NHt;
  ushort* lp = hT3 + 2 * NHt;
#pragma unroll
  for (int im = 0; im < 2; ++im)
#pragma unroll
    for (int in = 0; in < 2; ++in)
#pragma unroll
      for (int r = 0; r < 4; ++r) {
        int p = bm + wm + im * 16 + lg * 4 + r;
        if (p < cnt) {
          int col = bn + wn + in * 16 + lr;
          int g = rl[p];
          size_t idx = (size_t)p * HH + col;
          float hh = tanhf(xh[(size_t)g * HH + col] + acc[im][in][r]);
          float zz = zb[idx];
          float hv = (1.0f - zz) * hsf[idx] + zz * hh;
          ushort h, m, l;
          split1(hv, h, m, l);
          size_t tix = (size_t)col * NNODE + g;
          hp[tix] = h; mp[tix] = m; lp[tix] = l;
        }
      }
}

// -------- decoder: out = h @ dec_w^T + dec_b (h from 3-plane hT) -----------
__global__ __launch_bounds__(256) void decoder6(const ushort* __restrict__ hT3,
                                                const float* __restrict__ w,
                                                const float* __restrict__ b,
                                                float* __restrict__ out) {
  int g = blockIdx.x * 256 + threadIdx.x;
  float a0 = 0.f, a1 = 0.f, a2 = 0.f, a3 = 0.f;
  for (int c = 0; c < HH; ++c) {
    size_t idx = (size_t)c * NNODE + g;
    float hv = bf2f(hT3[idx]) + bf2f(hT3[NHt + idx]) + bf2f(hT3[2 * NHt + idx]);
    a0 = fmaf(hv, w[c], a0);
    a1 = fmaf(hv, w[HH + c], a1);
    a2 = fmaf(hv, w[2 * HH + c], a2);
    a3 = fmaf(hv, w[3 * HH + c], a3);
  }
  out[(size_t)g * 4 + 0] = a0 + b[0];
  out[(size_t)g * 4 + 1] = a1 + b[1];
  out[(size_t)g * 4 + 2] = a2 + b[2];
  out[(size_t)g * 4 + 3] = a3 + b[3];
}

extern "C" void kernel_launch(void* const* d_in, const int* in_sizes, int n_in,
                              void* d_out, int out_size, void* d_ws,
                              size_t ws_size, hipStream_t stream) {
  const float* x   = (const float*)d_in[0];
  const float* adj = (const float*)d_in[1];
  const int* level = (const int*)d_in[2];
  const float* E_w = (const float*)d_in[3];
  const float* Wr  = (const float*)d_in[4];
  const float* Wz  = (const float*)d_in[5];
  const float* Ur  = (const float*)d_in[6];
  const float* Uz  = (const float*)d_in[7];
  const float* Wh  = (const float*)d_in[8];
  const float* Uh  = (const float*)d_in[9];
  const float* dw  = (const float*)d_in[10];
  const float* db  = (const float*)d_in[11];

  // workspace (16B-aligned chunks)
  char* wp = (char*)d_ws;
  ushort* u3   = (ushort*)wp; wp += (size_t)3 * 3 * HH * HH * 2;   // 4.5 MiB
  ushort* xh3  = (ushort*)wp; wp += (size_t)3 * NHt * 2;           // 12 MiB
  float*  xrzh = (float*)wp;  wp += (size_t)3 * NHt * 4;           // 24 MiB
  ushort* hT3  = (ushort*)wp; wp += (size_t)3 * NHt * 2;           // 12 MiB
  float*  hsf  = (float*)wp;  wp += (size_t)PMAX * HH * 4;         // 1.5 MiB
  ushort* hs3  = (ushort*)wp; wp += (size_t)3 * PMAX * HH * 2;     // 2.25 MiB
  float*  part = (float*)wp;  wp += (size_t)AKS * PMAX * HH * 4;   // 6 MiB
  int* counts  = (int*)wp;    wp += 64;
  int* rowsl   = (int*)wp;    wp += (size_t)LL * NNODE * 4;
  if (ws_size < (size_t)(wp - (char*)d_ws)) return;  // ~65.4 MiB

  // tb3/zb alias the (dead-between-levels) part arena
  ushort* tb3 = (ushort*)part;
  float* zb = (float*)((char*)part + (size_t)3 * PMAX * HH * 2);

  hipMemsetAsync(counts, 0, 64, stream);
  hipMemsetAsync(hT3, 0, (size_t)3 * NHt * 2, stream);
  // hsf + hs3 are contiguous: zero both for level L-1 (agg skipped, h == 0)
  hipMemsetAsync(hsf, 0, (size_t)PMAX * HH * 4 + (size_t)3 * PMAX * HH * 2, stream);

  build_lists<<<(NNODE + 255) / 256, 256, 0, stream>>>(level, counts, rowsl, NNODE);
  cast_u3<<<dim3(HH * HH / 8 / 256, 3), 256, 0, stream>>>(Ur, Uz, Uh, u3);
  gemm_xhat6<<<dim3(NNODE / 64, HH / 128), 256, 0, stream>>>(x, E_w, xh3);
  gemm_w36<<<dim3(NNODE / 64, HH / 128, 3), 256, 0, stream>>>(xh3, Wr, Wz, Wh, xrzh);

  const float* xr = xrzh;
  const float* xz = xrzh + (size_t)NHt;
  const float* xhp = xrzh + (size_t)2 * NHt;
  const dim3 ggrid(PMAX / 64, HH / 64);
  for (int j = LL - 1; j >= 0; --j) {
    if (j != LL - 1) {
      agg6<<<dim3(PMAX / 64, HH / 128, AKS), 256, 0, stream>>>(adj, hT3, rowsl,
                                                               counts, j, part);
      agg_reduce6<<<PMAX * HH / 4 / 256, 256, 0, stream>>>(part, hsf, hs3);
    }
    gates_rz6<<<ggrid, 256, 0, stream>>>(hs3, u3, xr, xz, hsf, rowsl, counts, j,
                                         tb3, zb);
    gates_h6<<<ggrid, 256, 0, stream>>>(tb3, u3, xhp, hsf, zb, rowsl, counts, j,
                                        hT3);
  }
  decoder6<<<dim3(NNODE / 256), 256, 0, stream>>>(hT3, dw, db, (float*)d_out);
}

// Round 5
// 921.448 us; speedup vs baseline: 3.7328x; 1.3217x over previous
//
#include <hip/hip_runtime.h>
#include <math.h>

// Round 4: same 6xBF16 fp32-emulation numerics as round 3 (absmax was
// bit-identical to fp32), attack the occupancy/latency wall:
//  - x_hat: split-K=2 -> 512 blocks (was 256 = 1 blk/CU); fp32 partials
//    alias xrzh; combine+split kernel.
//  - Pre-split Wr/Wz/Wh + Ur/Uz/Uh planes once -> gate/w36 staging = copies.
//  - agg split-K 4->8 -> 256 active blocks.
//  - gates_rz: concat B'=[Ur;Uz] -> one gemm, grid (12,16), 64x64 tiles.
//  - level 7 closed form: h = sig(xz)*tanh(xh) (elementwise).
//  - aliases: xh3=hT3, xhat partials=xrzh[0:2NH], tb3/zb=part arena.

#define NNODE 4096
#define DD 5000
#define HH 512
#define HHHH 262144        // HH*HH
#define LL 8
#define PMAX 768           // max rows/level (Binom(4096,1/8)=512+-21; +12 sigma)
#define AKS 8              // agg split-K chunks
#define AKC 512            // NNODE/AKS
#define STR 40             // LDS row stride (ushorts)
#define NHt 2097152        // NNODE*HH

typedef __attribute__((ext_vector_type(8))) short short8v;
typedef __attribute__((ext_vector_type(4))) float float4v;

union fu { float f; unsigned u; };

__device__ __forceinline__ float sigf(float x) { return 1.0f / (1.0f + __expf(-x)); }
__device__ __forceinline__ float bf2f(ushort b) { fu v; v.u = ((unsigned)b) << 16; return v.f; }

// truncation split of a pair into packed u32 per plane (elem0=low16, elem1=high16)
__device__ __forceinline__ void splitpair(float a, float b, unsigned& hi,
                                          unsigned& mi, unsigned& lo) {
  const unsigned M = 0xFFFF0000u;
  fu A, B; A.f = a; B.f = b;
  hi = (A.u >> 16) | (B.u & M);
  fu Ah, Bh; Ah.u = A.u & M; Bh.u = B.u & M;
  float ra = a - Ah.f, rb = b - Bh.f;
  fu A1, B1; A1.f = ra; B1.f = rb;
  mi = (A1.u >> 16) | (B1.u & M);
  fu A1h, B1h; A1h.u = A1.u & M; B1h.u = B1.u & M;
  float ra2 = ra - A1h.f, rb2 = rb - B1h.f;
  fu A2, B2; A2.f = ra2; B2.f = rb2;
  lo = (A2.u >> 16) | (B2.u & M);
}

__device__ __forceinline__ void split8(const float* v, uint4& h, uint4& m, uint4& l) {
  splitpair(v[0], v[1], h.x, m.x, l.x);
  splitpair(v[2], v[3], h.y, m.y, l.y);
  splitpair(v[4], v[5], h.z, m.z, l.z);
  splitpair(v[6], v[7], h.w, m.w, l.w);
}

__device__ __forceinline__ void split1(float x, ushort& h, ushort& m, ushort& l) {
  const unsigned M = 0xFFFF0000u;
  fu a; a.f = x; h = (ushort)(a.u >> 16);
  fu ah; ah.u = a.u & M; float r = x - ah.f;
  fu b; b.f = r; m = (ushort)(b.u >> 16);
  fu bh; bh.u = b.u & M; float r2 = r - bh.f;
  fu c; c.f = r2; l = (ushort)(c.u >> 16);
}

// 6-product MFMA accumulate from 3-plane LDS tiles (A: 64 rows, B: BROWS rows).
// Product order MUST stay hh,hm,mh,hl,lh,mm (verified fp32-exact in round 3).
template <int NB, int BROWS>
__device__ __forceinline__ void mfma6(const ushort* As, const ushort* Bs,
                                      int wm, int wn, int lr, int lg8,
                                      float4v (*acc)[NB]) {
  short8v a[2][3];
#pragma unroll
  for (int im = 0; im < 2; ++im)
#pragma unroll
    for (int p = 0; p < 3; ++p)
      a[im][p] = *reinterpret_cast<const short8v*>(
          &As[(p * 64 + wm + 16 * im + lr) * STR + lg8]);
  short8v b[NB][3];
#pragma unroll
  for (int in = 0; in < NB; ++in)
#pragma unroll
    for (int p = 0; p < 3; ++p)
      b[in][p] = *reinterpret_cast<const short8v*>(
          &Bs[(p * BROWS + wn + 16 * in + lr) * STR + lg8]);
#pragma unroll
  for (int im = 0; im < 2; ++im)
#pragma unroll
    for (int in = 0; in < NB; ++in) {
      float4v c = acc[im][in];
      c = __builtin_amdgcn_mfma_f32_16x16x32_bf16(a[im][0], b[in][0], c, 0, 0, 0);
      c = __builtin_amdgcn_mfma_f32_16x16x32_bf16(a[im][0], b[in][1], c, 0, 0, 0);
      c = __builtin_amdgcn_mfma_f32_16x16x32_bf16(a[im][1], b[in][0], c, 0, 0, 0);
      c = __builtin_amdgcn_mfma_f32_16x16x32_bf16(a[im][0], b[in][2], c, 0, 0, 0);
      c = __builtin_amdgcn_mfma_f32_16x16x32_bf16(a[im][2], b[in][0], c, 0, 0, 0);
      c = __builtin_amdgcn_mfma_f32_16x16x32_bf16(a[im][1], b[in][1], c, 0, 0, 0);
      acc[im][in] = c;
    }
}

// -------- per-level row lists ----------------------------------------------
__global__ __launch_bounds__(256) void build_lists(const int* __restrict__ level,
                                                   int* __restrict__ counts,
                                                   int* __restrict__ rows, int N) {
  int i = blockIdx.x * blockDim.x + threadIdx.x;
  if (i < N) {
    int j = level[i];
    int p = atomicAdd(&counts[j], 1);
    rows[(size_t)j * N + p] = i;
  }
}

// -------- pre-split all 6 HxH weights into 3-plane arenas -------------------
// y=0: Ur -> urz3 rows 0-511; y=1: Uz -> urz3 rows 512-1023; y=2: Uh -> uh3;
// y=3..5: Wr/Wz/Wh -> w3s[mat].
__global__ __launch_bounds__(256) void cast_all(
    const float* __restrict__ Ur, const float* __restrict__ Uz,
    const float* __restrict__ Uh, const float* __restrict__ Wr,
    const float* __restrict__ Wz, const float* __restrict__ Wh,
    ushort* __restrict__ urz3, ushort* __restrict__ uh3,
    ushort* __restrict__ w3s) {
  const int y = blockIdx.y;
  const float* src = (y == 0) ? Ur : (y == 1) ? Uz : (y == 2) ? Uh
                   : (y == 3) ? Wr : (y == 4) ? Wz : Wh;
  ushort* dst; size_t ps, off;
  if (y <= 1)      { dst = urz3; ps = 2 * (size_t)HHHH; off = (size_t)y * HHHH; }
  else if (y == 2) { dst = uh3;  ps = HHHH; off = 0; }
  else             { dst = w3s + (size_t)(y - 3) * 3 * HHHH; ps = HHHH; off = 0; }
  int i = (blockIdx.x * 256 + threadIdx.x) * 8;
  float4 t0 = *reinterpret_cast<const float4*>(src + i);
  float4 t1 = *reinterpret_cast<const float4*>(src + i + 4);
  float v[8] = {t0.x, t0.y, t0.z, t0.w, t1.x, t1.y, t1.z, t1.w};
  uint4 h, m, l;
  split8(v, h, m, l);
  *reinterpret_cast<uint4*>(dst + off + i) = h;
  *reinterpret_cast<uint4*>(dst + ps + off + i) = m;
  *reinterpret_cast<uint4*>(dst + 2 * ps + off + i) = l;
}

// -------- x_hat partials: part[z] = x[:, kb:ke) @ E_w[:, kb:ke)^T ----------
__global__ __launch_bounds__(256) void gemm_xhat_sk(const float* __restrict__ x,
                                                    const float* __restrict__ Ew,
                                                    float* __restrict__ part) {
  __shared__ ushort As[3 * 64 * STR];
  __shared__ ushort Bs[3 * 128 * STR];
  const int z = blockIdx.z;
  const int kb = z * 2496;
  const int ke = z ? DD : 2496;
  const int tid = threadIdx.x;
  const int bm = blockIdx.x * 64, bn = blockIdx.y * 128;
  const int wid = tid >> 6, lane = tid & 63;
  const int lr = lane & 15, lg = lane >> 4, lg8 = lg * 8;
  const int wm = (wid >> 1) * 32, wn = (wid & 1) * 64;
  const int ar = tid >> 2, akq = (tid & 3) * 8;
  const int br = tid >> 1, bkq = (tid & 1) * 16;
  const float* ap = x + (size_t)(bm + ar) * DD + kb + akq;
  const float* bp = Ew + (size_t)(bn + br) * DD + kb + bkq;
  float4v acc[2][4];
#pragma unroll
  for (int i = 0; i < 2; ++i)
#pragma unroll
    for (int j = 0; j < 4; ++j) acc[i][j] = (float4v){0.f, 0.f, 0.f, 0.f};
  uint4 ah, am, al, bh0, bm0, bl0, bh1, bm1, bl1;
  auto loadA = [&](int k0) {
    float v[8];
    if (k0 + 32 <= ke) {
      float4 t0 = *reinterpret_cast<const float4*>(ap);
      float4 t1 = *reinterpret_cast<const float4*>(ap + 4);
      v[0]=t0.x; v[1]=t0.y; v[2]=t0.z; v[3]=t0.w;
      v[4]=t1.x; v[5]=t1.y; v[6]=t1.z; v[7]=t1.w;
    } else {
#pragma unroll
      for (int i = 0; i < 8; ++i) v[i] = (k0 + akq + i < ke) ? ap[i] : 0.0f;
    }
    split8(v, ah, am, al);
    ap += 32;
  };
  auto loadB = [&](int k0) {
    float v[16];
    if (k0 + 32 <= ke) {
      float4 t0 = *reinterpret_cast<const float4*>(bp);
      float4 t1 = *reinterpret_cast<const float4*>(bp + 4);
      float4 t2 = *reinterpret_cast<const float4*>(bp + 8);
      float4 t3 = *reinterpret_cast<const float4*>(bp + 12);
      v[0]=t0.x; v[1]=t0.y; v[2]=t0.z; v[3]=t0.w;
      v[4]=t1.x; v[5]=t1.y; v[6]=t1.z; v[7]=t1.w;
      v[8]=t2.x; v[9]=t2.y; v[10]=t2.z; v[11]=t2.w;
      v[12]=t3.x; v[13]=t3.y; v[14]=t3.z; v[15]=t3.w;
    } else {
#pragma unroll
      for (int i = 0; i < 16; ++i) v[i] = (k0 + bkq + i < ke) ? bp[i] : 0.0f;
    }
    split8(v, bh0, bm0, bl0);
    split8(v + 8, bh1, bm1, bl1);
    bp += 32;
  };
  loadA(kb); loadB(kb);
  for (int k0 = kb; k0 < ke; k0 += 32) {
    __syncthreads();
    *reinterpret_cast<uint4*>(&As[(0 * 64 + ar) * STR + akq]) = ah;
    *reinterpret_cast<uint4*>(&As[(1 * 64 + ar) * STR + akq]) = am;
    *reinterpret_cast<uint4*>(&As[(2 * 64 + ar) * STR + akq]) = al;
    *reinterpret_cast<uint4*>(&Bs[(0 * 128 + br) * STR + bkq]) = bh0;
    *reinterpret_cast<uint4*>(&Bs[(0 * 128 + br) * STR + bkq + 8]) = bh1;
    *reinterpret_cast<uint4*>(&Bs[(1 * 128 + br) * STR + bkq]) = bm0;
    *reinterpret_cast<uint4*>(&Bs[(1 * 128 + br) * STR + bkq + 8]) = bm1;
    *reinterpret_cast<uint4*>(&Bs[(2 * 128 + br) * STR + bkq]) = bl0;
    *reinterpret_cast<uint4*>(&Bs[(2 * 128 + br) * STR + bkq + 8]) = bl1;
    __syncthreads();
    if (k0 + 32 < ke) { loadA(k0 + 32); loadB(k0 + 32); }
    mfma6<4, 128>(As, Bs, wm, wn, lr, lg8, acc);
  }
  float* C = part + (size_t)z * NHt;
#pragma unroll
  for (int im = 0; im < 2; ++im)
#pragma unroll
    for (int in = 0; in < 4; ++in)
#pragma unroll
      for (int r = 0; r < 4; ++r)
        C[(size_t)(bm + wm + im * 16 + lg * 4 + r) * HH + bn + wn + in * 16 + lr] =
            acc[im][in][r];
}

// -------- x_hat = part0 + part1, split to 3 planes -------------------------
__global__ __launch_bounds__(256) void combine_split(const float* __restrict__ p,
                                                     ushort* __restrict__ xh3) {
  int i = (blockIdx.x * 256 + threadIdx.x) * 8;
  float4 a0 = *reinterpret_cast<const float4*>(p + i);
  float4 a1 = *reinterpret_cast<const float4*>(p + i + 4);
  float4 b0 = *reinterpret_cast<const float4*>(p + NHt + i);
  float4 b1 = *reinterpret_cast<const float4*>(p + NHt + i + 4);
  float v[8] = {a0.x + b0.x, a0.y + b0.y, a0.z + b0.z, a0.w + b0.w,
                a1.x + b1.x, a1.y + b1.y, a1.z + b1.z, a1.w + b1.w};
  uint4 h, m, l;
  split8(v, h, m, l);
  *reinterpret_cast<uint4*>(xh3 + i) = h;
  *reinterpret_cast<uint4*>(xh3 + NHt + i) = m;
  *reinterpret_cast<uint4*>(xh3 + 2 * (size_t)NHt + i) = l;
}

// -------- xr/xz/xh = x_hat @ {Wr,Wz,Wh}^T (both sides pre-split) -----------
__global__ __launch_bounds__(256) void gemm_w36(const ushort* __restrict__ xh3,
                                                const ushort* __restrict__ w3s,
                                                float* __restrict__ xrzh) {
  const int z = blockIdx.z;
  const ushort* B = w3s + (size_t)z * 3 * HHHH;
  float* C = xrzh + (size_t)z * NHt;
  __shared__ ushort As[3 * 64 * STR];
  __shared__ ushort Bs[3 * 128 * STR];
  const int tid = threadIdx.x;
  const int bm = blockIdx.x * 64, bn = blockIdx.y * 128;
  const int wid = tid >> 6, lane = tid & 63;
  const int lr = lane & 15, lg = lane >> 4, lg8 = lg * 8;
  const int wm = (wid >> 1) * 32, wn = (wid & 1) * 64;
  const int ar = tid >> 2, akq = (tid & 3) * 8;
  const int br = tid >> 1, bkq = (tid & 1) * 16;
  const ushort* aph = xh3 + (size_t)(bm + ar) * HH + akq;
  const ushort* bph = B + (size_t)(bn + br) * HH + bkq;
  float4v acc[2][4];
#pragma unroll
  for (int i = 0; i < 2; ++i)
#pragma unroll
    for (int j = 0; j < 4; ++j) acc[i][j] = (float4v){0.f, 0.f, 0.f, 0.f};
  short8v a3[3], b0[3], b1[3];
  auto loadAll = [&]() {
#pragma unroll
    for (int p = 0; p < 3; ++p) {
      a3[p] = *reinterpret_cast<const short8v*>(aph + (size_t)p * NHt);
      b0[p] = *reinterpret_cast<const short8v*>(bph + (size_t)p * HHHH);
      b1[p] = *reinterpret_cast<const short8v*>(bph + (size_t)p * HHHH + 8);
    }
    aph += 32; bph += 32;
  };
  loadAll();
  for (int k0 = 0; k0 < HH; k0 += 32) {
    __syncthreads();
#pragma unroll
    for (int p = 0; p < 3; ++p) {
      *reinterpret_cast<short8v*>(&As[(p * 64 + ar) * STR + akq]) = a3[p];
      *reinterpret_cast<short8v*>(&Bs[(p * 128 + br) * STR + bkq]) = b0[p];
      *reinterpret_cast<short8v*>(&Bs[(p * 128 + br) * STR + bkq + 8]) = b1[p];
    }
    __syncthreads();
    if (k0 + 32 < HH) loadAll();
    mfma6<4, 128>(As, Bs, wm, wn, lr, lg8, acc);
  }
#pragma unroll
  for (int im = 0; im < 2; ++im)
#pragma unroll
    for (int in = 0; in < 4; ++in)
#pragma unroll
      for (int r = 0; r < 4; ++r)
        C[(size_t)(bm + wm + im * 16 + lg * 4 + r) * HH + bn + wn + in * 16 + lr] =
            acc[im][in][r];
}

// -------- agg split-K: part[z][p][n] = adj[rows[p], kb:kb+AKC) @ h ---------
__global__ __launch_bounds__(256) void agg6(const float* __restrict__ adj,
                                            const ushort* __restrict__ hT3,
                                            const int* __restrict__ rows,
                                            const int* __restrict__ counts,
                                            int lvl, float* __restrict__ part) {
  const int cnt = min(counts[lvl], PMAX);
  const int bm = blockIdx.x * 64;
  if (bm >= cnt) return;
  const int* rl = rows + (size_t)lvl * NNODE;
  const int kb = blockIdx.z * AKC;
  const int bn = blockIdx.y * 128;
  __shared__ ushort As[3 * 64 * STR];
  __shared__ ushort Bs[3 * 128 * STR];
  const int tid = threadIdx.x;
  const int wid = tid >> 6, lane = tid & 63;
  const int lr = lane & 15, lg = lane >> 4, lg8 = lg * 8;
  const int wm = (wid >> 1) * 32, wn = (wid & 1) * 64;
  const int ar = tid >> 2, akq = (tid & 3) * 8;
  const int br = tid >> 1, bkq = (tid & 1) * 16;
  int p0 = bm + ar;
  if (p0 >= cnt) p0 = cnt - 1;  // clamp: duplicate row, never stored
  const float* ap = adj + (size_t)rl[p0] * NNODE + kb + akq;
  const ushort* bph = hT3 + (size_t)(bn + br) * NNODE + kb + bkq;
  float4v acc[2][4];
#pragma unroll
  for (int i = 0; i < 2; ++i)
#pragma unroll
    for (int j = 0; j < 4; ++j) acc[i][j] = (float4v){0.f, 0.f, 0.f, 0.f};
  uint4 ah, am, al;
  short8v b0[3], b1[3];
  auto loadA = [&]() {
    float4 t0 = *reinterpret_cast<const float4*>(ap);
    float4 t1 = *reinterpret_cast<const float4*>(ap + 4);
    float v[8] = {t0.x, t0.y, t0.z, t0.w, t1.x, t1.y, t1.z, t1.w};
    split8(v, ah, am, al);
    ap += 32;
  };
  auto loadB = [&]() {
#pragma unroll
    for (int p = 0; p < 3; ++p) {
      b0[p] = *reinterpret_cast<const short8v*>(bph + (size_t)p * NHt);
      b1[p] = *reinterpret_cast<const short8v*>(bph + (size_t)p * NHt + 8);
    }
    bph += 32;
  };
  loadA(); loadB();
  for (int k0 = 0; k0 < AKC; k0 += 32) {
    __syncthreads();
    *reinterpret_cast<uint4*>(&As[(0 * 64 + ar) * STR + akq]) = ah;
    *reinterpret_cast<uint4*>(&As[(1 * 64 + ar) * STR + akq]) = am;
    *reinterpret_cast<uint4*>(&As[(2 * 64 + ar) * STR + akq]) = al;
#pragma unroll
    for (int p = 0; p < 3; ++p) {
      *reinterpret_cast<short8v*>(&Bs[(p * 128 + br) * STR + bkq]) = b0[p];
      *reinterpret_cast<short8v*>(&Bs[(p * 128 + br) * STR + bkq + 8]) = b1[p];
    }
    __syncthreads();
    if (k0 + 32 < AKC) { loadA(); loadB(); }
    mfma6<4, 128>(As, Bs, wm, wn, lr, lg8, acc);
  }
  float* cp = part + (size_t)blockIdx.z * PMAX * HH;
#pragma unroll
  for (int im = 0; im < 2; ++im)
#pragma unroll
    for (int in = 0; in < 4; ++in)
#pragma unroll
      for (int r = 0; r < 4; ++r) {
        int p = bm + wm + im * 16 + lg * 4 + r;
        if (p < cnt)
          cp[(size_t)p * HH + bn + wn + in * 16 + lr] = acc[im][in][r];
      }
}

// -------- hs = sum_z part[z]; write fp32 + 3-plane split -------------------
__global__ __launch_bounds__(256) void agg_reduce6(const float* __restrict__ part,
                                                   float* __restrict__ hsf,
                                                   ushort* __restrict__ hs3) {
  int id = blockIdx.x * 256 + threadIdx.x;  // PMAX*HH/4 threads
  const int zs = PMAX * HH / 4;
  const float4* q = reinterpret_cast<const float4*>(part) + id;
  float4 s = q[0];
#pragma unroll
  for (int z = 1; z < AKS; ++z) {
    float4 t = q[(size_t)z * zs];
    s.x += t.x; s.y += t.y; s.z += t.z; s.w += t.w;
  }
  reinterpret_cast<float4*>(hsf)[id] = s;
  unsigned h0, m0, l0, h1, m1, l1;
  splitpair(s.x, s.y, h0, m0, l0);
  splitpair(s.z, s.w, h1, m1, l1);
  *reinterpret_cast<uint2*>(hs3 + (size_t)id * 4) = make_uint2(h0, h1);
  *reinterpret_cast<uint2*>(hs3 + PMAX * HH + (size_t)id * 4) = make_uint2(m0, m1);
  *reinterpret_cast<uint2*>(hs3 + 2 * PMAX * HH + (size_t)id * 4) = make_uint2(l0, l1);
}

// -------- r,z gates on concat B'=[Ur;Uz]: 64x64 tiles, grid (12,16) --------
__global__ __launch_bounds__(256) void gates_rz6(
    const ushort* __restrict__ hs3, const ushort* __restrict__ urz3,
    const float* __restrict__ xr, const float* __restrict__ xz,
    const float* __restrict__ hsf, const int* __restrict__ rows,
    const int* __restrict__ counts, int lvl, ushort* __restrict__ tb3,
    float* __restrict__ zb) {
  const int cnt = min(counts[lvl], PMAX);
  const int bm = blockIdx.x * 64;
  if (bm >= cnt) return;
  const int* rl = rows + (size_t)lvl * NNODE;
  const int bn = blockIdx.y * 64;  // 0..1023 over [Ur;Uz]
  __shared__ ushort As[3 * 64 * STR];
  __shared__ ushort Bs[3 * 64 * STR];
  const int tid = threadIdx.x;
  const int wid = tid >> 6, lane = tid & 63;
  const int lr = lane & 15, lg = lane >> 4, lg8 = lg * 8;
  const int wm = (wid >> 1) * 32, wn = (wid & 1) * 32;
  const int ar = tid >> 2, akq = (tid & 3) * 8;
  const ushort* aph = hs3 + (size_t)(bm + ar) * HH + akq;
  const ushort* bph = urz3 + (size_t)(bn + ar) * HH + akq;
  float4v acc[2][2];
#pragma unroll
  for (int i = 0; i < 2; ++i)
#pragma unroll
    for (int j = 0; j < 2; ++j) acc[i][j] = (float4v){0.f, 0.f, 0.f, 0.f};
  short8v a3[3], b3[3];
  auto loadAll = [&]() {
#pragma unroll
    for (int p = 0; p < 3; ++p) {
      a3[p] = *reinterpret_cast<const short8v*>(aph + (size_t)p * PMAX * HH);
      b3[p] = *reinterpret_cast<const short8v*>(bph + (size_t)p * 2 * HHHH);
    }
    aph += 32; bph += 32;
  };
  loadAll();
  for (int k0 = 0; k0 < HH; k0 += 32) {
    __syncthreads();
#pragma unroll
    for (int p = 0; p < 3; ++p) {
      *reinterpret_cast<short8v*>(&As[(p * 64 + ar) * STR + akq]) = a3[p];
      *reinterpret_cast<short8v*>(&Bs[(p * 64 + ar) * STR + akq]) = b3[p];
    }
    __syncthreads();
    if (k0 + 32 < HH) loadAll();
    mfma6<2, 64>(As, Bs, wm, wn, lr, lg8, acc);
  }
  ushort* th = tb3;
  ushort* tm = tb3 + PMAX * HH;
  ushort* tl = tb3 + 2 * PMAX * HH;
#pragma unroll
  for (int im = 0; im < 2; ++im)
#pragma unroll
    for (int in = 0; in < 2; ++in)
#pragma unroll
      for (int r = 0; r < 4; ++r) {
        int p = bm + wm + im * 16 + lg * 4 + r;
        if (p < cnt) {
          int col = bn + wn + in * 16 + lr;
          int g = rl[p];
          if (col < HH) {  // r-gate half
            float rr = sigf(xr[(size_t)g * HH + col] + acc[im][in][r]);
            float t = hsf[(size_t)p * HH + col] * rr;
            ushort h, m, l;
            split1(t, h, m, l);
            size_t idx = (size_t)p * HH + col;
            th[idx] = h; tm[idx] = m; tl[idx] = l;
          } else {  // z-gate half
            int c = col - HH;
            zb[(size_t)p * HH + c] = sigf(xz[(size_t)g * HH + c] + acc[im][in][r]);
          }
        }
      }
}

// -------- h-hat + update: hT3[col][g] = split((1-z)hs + z*tanh(xh+tb@Uh^T)) -
__global__ __launch_bounds__(256) void gates_h6(
    const ushort* __restrict__ tb3, const ushort* __restrict__ uh3,
    const float* __restrict__ xh, const float* __restrict__ hsf,
    const float* __restrict__ zb, const int* __restrict__ rows,
    const int* __restrict__ counts, int lvl, ushort* __restrict__ hT3) {
  const int cnt = min(counts[lvl], PMAX);
  const int bm = blockIdx.x * 64;
  if (bm >= cnt) return;
  const int* rl = rows + (size_t)lvl * NNODE;
  const int bn = blockIdx.y * 64;
  __shared__ ushort As[3 * 64 * STR];
  __shared__ ushort Bs[3 * 64 * STR];
  const int tid = threadIdx.x;
  const int wid = tid >> 6, lane = tid & 63;
  const int lr = lane & 15, lg = lane >> 4, lg8 = lg * 8;
  const int wm = (wid >> 1) * 32, wn = (wid & 1) * 32;
  const int ar = tid >> 2, akq = (tid & 3) * 8;
  const ushort* aph = tb3 + (size_t)(bm + ar) * HH + akq;
  const ushort* bph = uh3 + (size_t)(bn + ar) * HH + akq;
  float4v acc[2][2];
#pragma unroll
  for (int i = 0; i < 2; ++i)
#pragma unroll
    for (int j = 0; j < 2; ++j) acc[i][j] = (float4v){0.f, 0.f, 0.f, 0.f};
  short8v a3[3], b3[3];
  auto loadAll = [&]() {
#pragma unroll
    for (int p = 0; p < 3; ++p) {
      a3[p] = *reinterpret_cast<const short8v*>(aph + (size_t)p * PMAX * HH);
      b3[p] = *reinterpret_cast<const short8v*>(bph + (size_t)p * HHHH);
    }
    aph += 32; bph += 32;
  };
  loadAll();
  for (int k0 = 0; k0 < HH; k0 += 32) {
    __syncthreads();
#pragma unroll
    for (int p = 0; p < 3; ++p) {
      *reinterpret_cast<short8v*>(&As[(p * 64 + ar) * STR + akq]) = a3[p];
      *reinterpret_cast<short8v*>(&Bs[(p * 64 + ar) * STR + akq]) = b3[p];
    }
    __syncthreads();
    if (k0 + 32 < HH) loadAll();
    mfma6<2, 64>(As, Bs, wm, wn, lr, lg8, acc);
  }
  ushort* hp = hT3;
  ushort* mp = hT3 + NHt;
  ushort* lp = hT3 + 2 * (size_t)NHt;
#pragma unroll
  for (int im = 0; im < 2; ++im)
#pragma unroll
    for (int in = 0; in < 2; ++in)
#pragma unroll
      for (int r = 0; r < 4; ++r) {
        int p = bm + wm + im * 16 + lg * 4 + r;
        if (p < cnt) {
          int col = bn + wn + in * 16 + lr;
          int g = rl[p];
          size_t idx = (size_t)p * HH + col;
          float hh = tanhf(xh[(size_t)g * HH + col] + acc[im][in][r]);
          float zz = zb[idx];
          float hv = (1.0f - zz) * hsf[idx] + zz * hh;
          ushort h, m, l;
          split1(hv, h, m, l);
          size_t tix = (size_t)col * NNODE + g;
          hp[tix] = h; mp[tix] = m; lp[tix] = l;
        }
      }
}

// -------- level L-1 closed form: h = sig(xz) * tanh(xh) --------------------
__global__ __launch_bounds__(256) void lvl7_init(const float* __restrict__ xz,
                                                 const float* __restrict__ xh,
                                                 const int* __restrict__ rows,
                                                 const int* __restrict__ counts,
                                                 ushort* __restrict__ hT3) {
  const int cnt = min(counts[LL - 1], PMAX);
  int idx = blockIdx.x * 256 + threadIdx.x;  // PMAX*HH/8 threads
  int p = idx >> 6;
  int c0 = (idx & 63) * 8;
  if (p >= cnt) return;
  int g = rows[(size_t)(LL - 1) * NNODE + p];
  float4 z0 = *reinterpret_cast<const float4*>(xz + (size_t)g * HH + c0);
  float4 z1 = *reinterpret_cast<const float4*>(xz + (size_t)g * HH + c0 + 4);
  float4 h0 = *reinterpret_cast<const float4*>(xh + (size_t)g * HH + c0);
  float4 h1 = *reinterpret_cast<const float4*>(xh + (size_t)g * HH + c0 + 4);
  float zv[8] = {z0.x, z0.y, z0.z, z0.w, z1.x, z1.y, z1.z, z1.w};
  float hv[8] = {h0.x, h0.y, h0.z, h0.w, h1.x, h1.y, h1.z, h1.w};
#pragma unroll
  for (int i = 0; i < 8; ++i) {
    float val = sigf(zv[i]) * tanhf(hv[i]);
    ushort h, m, l;
    split1(val, h, m, l);
    size_t tix = (size_t)(c0 + i) * NNODE + g;
    hT3[tix] = h;
    hT3[NHt + tix] = m;
    hT3[2 * (size_t)NHt + tix] = l;
  }
}

// -------- decoder: out = h @ dec_w^T + dec_b (h from 3-plane hT) -----------
__global__ __launch_bounds__(256) void decoder6(const ushort* __restrict__ hT3,
                                                const float* __restrict__ w,
                                                const float* __restrict__ b,
                                                float* __restrict__ out) {
  int g = blockIdx.x * 256 + threadIdx.x;
  float a0 = 0.f, a1 = 0.f, a2 = 0.f, a3 = 0.f;
#pragma unroll 4
  for (int c = 0; c < HH; ++c) {
    size_t idx = (size_t)c * NNODE + g;
    float hv = bf2f(hT3[idx]) + bf2f(hT3[NHt + idx]) + bf2f(hT3[2 * (size_t)NHt + idx]);
    a0 = fmaf(hv, w[c], a0);
    a1 = fmaf(hv, w[HH + c], a1);
    a2 = fmaf(hv, w[2 * HH + c], a2);
    a3 = fmaf(hv, w[3 * HH + c], a3);
  }
  out[(size_t)g * 4 + 0] = a0 + b[0];
  out[(size_t)g * 4 + 1] = a1 + b[1];
  out[(size_t)g * 4 + 2] = a2 + b[2];
  out[(size_t)g * 4 + 3] = a3 + b[3];
}

extern "C" void kernel_launch(void* const* d_in, const int* in_sizes, int n_in,
                              void* d_out, int out_size, void* d_ws,
                              size_t ws_size, hipStream_t stream) {
  const float* x   = (const float*)d_in[0];
  const float* adj = (const float*)d_in[1];
  const int* level = (const int*)d_in[2];
  const float* E_w = (const float*)d_in[3];
  const float* Wr  = (const float*)d_in[4];
  const float* Wz  = (const float*)d_in[5];
  const float* Ur  = (const float*)d_in[6];
  const float* Uz  = (const float*)d_in[7];
  const float* Wh  = (const float*)d_in[8];
  const float* Uh  = (const float*)d_in[9];
  const float* dw  = (const float*)d_in[10];
  const float* db  = (const float*)d_in[11];

  // workspace layout (16B-aligned chunks)
  char* wp = (char*)d_ws;
  ushort* urz3 = (ushort*)wp; wp += (size_t)3 * 2 * HHHH * 2;   // 3.1 MB
  ushort* uh3  = (ushort*)wp; wp += (size_t)3 * HHHH * 2;       // 1.5 MB
  ushort* w3s  = (ushort*)wp; wp += (size_t)3 * 3 * HHHH * 2;   // 4.7 MB
  ushort* hT3  = (ushort*)wp; wp += (size_t)3 * NHt * 2;        // 12.6 MB (xh3 alias)
  float*  xrzh = (float*)wp;  wp += (size_t)3 * NHt * 4;        // 25.2 MB (xhat partials alias)
  float*  hsf  = (float*)wp;  wp += (size_t)PMAX * HH * 4;      // 1.5 MB
  ushort* hs3  = (ushort*)wp; wp += (size_t)3 * PMAX * HH * 2;  // 2.25 MB
  float*  part = (float*)wp;  wp += (size_t)AKS * PMAX * HH * 4;// 12.6 MB (tb3/zb alias)
  int* counts  = (int*)wp;    wp += 64;
  int* rowsl   = (int*)wp;    wp += (size_t)LL * NNODE * 4;
  if (ws_size < (size_t)(wp - (char*)d_ws)) return;  // ~63.6 MB

  ushort* xh3 = hT3;                 // x_hat planes live before hT3 is needed
  float* xpart = xrzh;               // x_hat split-K partials (2 planes)
  ushort* tb3 = (ushort*)part;       // dead between agg_reduce and next agg6
  float* zb = (float*)((char*)part + (size_t)3 * PMAX * HH * 2);

  hipMemsetAsync(counts, 0, 64, stream);
  build_lists<<<(NNODE + 255) / 256, 256, 0, stream>>>(level, counts, rowsl, NNODE);
  cast_all<<<dim3(HHHH / 8 / 256, 6), 256, 0, stream>>>(Ur, Uz, Uh, Wr, Wz, Wh,
                                                        urz3, uh3, w3s);
  gemm_xhat_sk<<<dim3(NNODE / 64, HH / 128, 2), 256, 0, stream>>>(x, E_w, xpart);
  combine_split<<<NHt / 8 / 256, 256, 0, stream>>>(xpart, xh3);
  gemm_w36<<<dim3(NNODE / 64, HH / 128, 3), 256, 0, stream>>>(xh3, w3s, xrzh);

  const float* xr  = xrzh;
  const float* xzp = xrzh + (size_t)NHt;
  const float* xhp = xrzh + (size_t)2 * NHt;

  // xh3 is dead after gemm_w36 -> zero the region as h-state (hT3)
  hipMemsetAsync(hT3, 0, (size_t)3 * NHt * 2, stream);
  lvl7_init<<<PMAX * HH / 8 / 256, 256, 0, stream>>>(xzp, xhp, rowsl, counts, hT3);

  for (int j = LL - 2; j >= 0; --j) {
    agg6<<<dim3(PMAX / 64, HH / 128, AKS), 256, 0, stream>>>(adj, hT3, rowsl,
                                                             counts, j, part);
    agg_reduce6<<<PMAX * HH / 4 / 256, 256, 0, stream>>>(part, hsf, hs3);
    gates_rz6<<<dim3(PMAX / 64, 2 * HH / 64), 256, 0, stream>>>(
        hs3, urz3, xr, xzp, hsf, rowsl, counts, j, tb3, zb);
    gates_h6<<<dim3(PMAX / 64, HH / 64), 256, 0, stream>>>(
        tb3, uh3, xhp, hsf, zb, rowsl, counts, j, hT3);
  }
  decoder6<<<dim3(NNODE / 256), 256, 0, stream>>>(hT3, dw, db, (float*)d_out);
}

// Round 6
// 801.618 us; speedup vs baseline: 4.2908x; 1.1495x over previous
//
#include <hip/hip_runtime.h>
#include <math.h>

// Round 5: same 6xBF16 fp32-emulation numerics as rounds 3/4 (absmax was
// bit-identical to fp32 = 4.398e12). Parallelism/staging round:
//  - E_w pre-split into 3 zero-padded [512][5024] bf16 planes -> x_hat B-side
//    staging is pure copies (was 96 redundant split-VALU/thread/iter).
//  - x_hat split-K=3 -> 768 blocks = 3 blk/CU (was 512 = 2).
//  - 32-row M-tiles in the level loop: agg6 512 active blocks (2/CU),
//    gates_rz 256, gates_h 128 (were 256/128/64).
//  - decoder: 4 threads/row + shfl (64 blocks, was 16).
//  - PMAX 768->640 (+6 sigma) to fit Ew3 arena: total ws ~64.4 MB (<67 proven).

#define NNODE 4096
#define DD 5000
#define DP 5024            // DD padded to 32
#define HH 512
#define HHHH 262144        // HH*HH
#define LL 8
#define PMAX 640           // max rows/level (Binom(4096,1/8)=512,s=21.2; +6s)
#define AKS 8              // agg split-K chunks
#define AKC 512            // NNODE/AKS
#define STR 40             // LDS row stride (ushorts)
#define NHt 2097152        // NNODE*HH
#define XCH 1696           // x_hat K-chunk (53*32; 3 chunks cover 5024)
#define EWP (HH * DP)      // E_w plane size

typedef __attribute__((ext_vector_type(8))) short short8v;
typedef __attribute__((ext_vector_type(4))) float float4v;

union fu { float f; unsigned u; };

__device__ __forceinline__ float sigf(float x) { return 1.0f / (1.0f + __expf(-x)); }
__device__ __forceinline__ float bf2f(ushort b) { fu v; v.u = ((unsigned)b) << 16; return v.f; }

// truncation split of a pair into packed u32 per plane (elem0=low16, elem1=high16)
__device__ __forceinline__ void splitpair(float a, float b, unsigned& hi,
                                          unsigned& mi, unsigned& lo) {
  const unsigned M = 0xFFFF0000u;
  fu A, B; A.f = a; B.f = b;
  hi = (A.u >> 16) | (B.u & M);
  fu Ah, Bh; Ah.u = A.u & M; Bh.u = B.u & M;
  float ra = a - Ah.f, rb = b - Bh.f;
  fu A1, B1; A1.f = ra; B1.f = rb;
  mi = (A1.u >> 16) | (B1.u & M);
  fu A1h, B1h; A1h.u = A1.u & M; B1h.u = B1.u & M;
  float ra2 = ra - A1h.f, rb2 = rb - B1h.f;
  fu A2, B2; A2.f = ra2; B2.f = rb2;
  lo = (A2.u >> 16) | (B2.u & M);
}

__device__ __forceinline__ void split8(const float* v, uint4& h, uint4& m, uint4& l) {
  splitpair(v[0], v[1], h.x, m.x, l.x);
  splitpair(v[2], v[3], h.y, m.y, l.y);
  splitpair(v[4], v[5], h.z, m.z, l.z);
  splitpair(v[6], v[7], h.w, m.w, l.w);
}

__device__ __forceinline__ void split1(float x, ushort& h, ushort& m, ushort& l) {
  const unsigned M = 0xFFFF0000u;
  fu a; a.f = x; h = (ushort)(a.u >> 16);
  fu ah; ah.u = a.u & M; float r = x - ah.f;
  fu b; b.f = r; m = (ushort)(b.u >> 16);
  fu bh; bh.u = b.u & M; float r2 = r - bh.f;
  fu c; c.f = r2; l = (ushort)(c.u >> 16);
}

// 6-product MFMA accumulate from 3-plane LDS tiles.
// Product order MUST stay hh,hm,mh,hl,lh,mm (verified fp32-exact, rounds 3/4).
template <int NB, int AROWS, int BROWS>
__device__ __forceinline__ void mfma6(const ushort* As, const ushort* Bs,
                                      int wm, int wn, int lr, int lg8,
                                      float4v (*acc)[NB]) {
  short8v a[2][3];
#pragma unroll
  for (int im = 0; im < 2; ++im)
#pragma unroll
    for (int p = 0; p < 3; ++p)
      a[im][p] = *reinterpret_cast<const short8v*>(
          &As[(p * AROWS + wm + 16 * im + lr) * STR + lg8]);
  short8v b[NB][3];
#pragma unroll
  for (int in = 0; in < NB; ++in)
#pragma unroll
    for (int p = 0; p < 3; ++p)
      b[in][p] = *reinterpret_cast<const short8v*>(
          &Bs[(p * BROWS + wn + 16 * in + lr) * STR + lg8]);
#pragma unroll
  for (int im = 0; im < 2; ++im)
#pragma unroll
    for (int in = 0; in < NB; ++in) {
      float4v c = acc[im][in];
      c = __builtin_amdgcn_mfma_f32_16x16x32_bf16(a[im][0], b[in][0], c, 0, 0, 0);
      c = __builtin_amdgcn_mfma_f32_16x16x32_bf16(a[im][0], b[in][1], c, 0, 0, 0);
      c = __builtin_amdgcn_mfma_f32_16x16x32_bf16(a[im][1], b[in][0], c, 0, 0, 0);
      c = __builtin_amdgcn_mfma_f32_16x16x32_bf16(a[im][0], b[in][2], c, 0, 0, 0);
      c = __builtin_amdgcn_mfma_f32_16x16x32_bf16(a[im][2], b[in][0], c, 0, 0, 0);
      c = __builtin_amdgcn_mfma_f32_16x16x32_bf16(a[im][1], b[in][1], c, 0, 0, 0);
      acc[im][in] = c;
    }
}

// -------- per-level row lists ----------------------------------------------
__global__ __launch_bounds__(256) void build_lists(const int* __restrict__ level,
                                                   int* __restrict__ counts,
                                                   int* __restrict__ rows, int N) {
  int i = blockIdx.x * blockDim.x + threadIdx.x;
  if (i < N) {
    int j = level[i];
    int p = atomicAdd(&counts[j], 1);
    rows[(size_t)j * N + p] = i;
  }
}

// -------- pre-split 6 HxH weights into 3-plane arenas -----------------------
__global__ __launch_bounds__(256) void cast_all(
    const float* __restrict__ Ur, const float* __restrict__ Uz,
    const float* __restrict__ Uh, const float* __restrict__ Wr,
    const float* __restrict__ Wz, const float* __restrict__ Wh,
    ushort* __restrict__ urz3, ushort* __restrict__ uh3,
    ushort* __restrict__ w3s) {
  const int y = blockIdx.y;
  const float* src = (y == 0) ? Ur : (y == 1) ? Uz : (y == 2) ? Uh
                   : (y == 3) ? Wr : (y == 4) ? Wz : Wh;
  ushort* dst; size_t ps, off;
  if (y <= 1)      { dst = urz3; ps = 2 * (size_t)HHHH; off = (size_t)y * HHHH; }
  else if (y == 2) { dst = uh3;  ps = HHHH; off = 0; }
  else             { dst = w3s + (size_t)(y - 3) * 3 * HHHH; ps = HHHH; off = 0; }
  int i = (blockIdx.x * 256 + threadIdx.x) * 8;
  float4 t0 = *reinterpret_cast<const float4*>(src + i);
  float4 t1 = *reinterpret_cast<const float4*>(src + i + 4);
  float v[8] = {t0.x, t0.y, t0.z, t0.w, t1.x, t1.y, t1.z, t1.w};
  uint4 h, m, l;
  split8(v, h, m, l);
  *reinterpret_cast<uint4*>(dst + off + i) = h;
  *reinterpret_cast<uint4*>(dst + ps + off + i) = m;
  *reinterpret_cast<uint4*>(dst + 2 * ps + off + i) = l;
}

// -------- pre-split E_w into 3 zero-padded [HH][DP] planes ------------------
__global__ __launch_bounds__(256) void cast_ew(const float* __restrict__ Ew,
                                               ushort* __restrict__ ew3) {
  int idx = (blockIdx.x * 256 + threadIdx.x) * 8;  // over HH*DP (DP%8==0)
  int row = idx / DP, col = idx % DP;
  float v[8];
  if (col + 8 <= DD) {
    float4 t0 = *reinterpret_cast<const float4*>(Ew + (size_t)row * DD + col);
    float4 t1 = *reinterpret_cast<const float4*>(Ew + (size_t)row * DD + col + 4);
    v[0]=t0.x; v[1]=t0.y; v[2]=t0.z; v[3]=t0.w;
    v[4]=t1.x; v[5]=t1.y; v[6]=t1.z; v[7]=t1.w;
  } else {
#pragma unroll
    for (int i = 0; i < 8; ++i)
      v[i] = (col + i < DD) ? Ew[(size_t)row * DD + col + i] : 0.0f;
  }
  uint4 h, m, l;
  split8(v, h, m, l);
  *reinterpret_cast<uint4*>(ew3 + idx) = h;
  *reinterpret_cast<uint4*>(ew3 + EWP + idx) = m;
  *reinterpret_cast<uint4*>(ew3 + 2 * (size_t)EWP + idx) = l;
}

// -------- x_hat partials: part[z] = x[:, kb:ke) @ E_w[:, kb:ke)^T -----------
__global__ __launch_bounds__(256) void gemm_xhat_sk(const float* __restrict__ x,
                                                    const ushort* __restrict__ ew3,
                                                    float* __restrict__ xpart) {
  __shared__ ushort As[3 * 64 * STR];
  __shared__ ushort Bs[3 * 128 * STR];
  const int z = blockIdx.z;
  const int kb = z * XCH;
  const int kePad = min(kb + XCH, DP);
  const int keReal = min(kePad, DD);
  const int tid = threadIdx.x;
  const int bm = blockIdx.x * 64, bn = blockIdx.y * 128;
  const int wid = tid >> 6, lane = tid & 63;
  const int lr = lane & 15, lg = lane >> 4, lg8 = lg * 8;
  const int wm = (wid >> 1) * 32, wn = (wid & 1) * 64;
  const int ar = tid >> 2, akq = (tid & 3) * 8;
  const int br = tid >> 1, bkq = (tid & 1) * 16;
  const float* ap = x + (size_t)(bm + ar) * DD + kb + akq;
  const ushort* bph = ew3 + (size_t)(bn + br) * DP + kb + bkq;
  float4v acc[2][4];
#pragma unroll
  for (int i = 0; i < 2; ++i)
#pragma unroll
    for (int j = 0; j < 4; ++j) acc[i][j] = (float4v){0.f, 0.f, 0.f, 0.f};
  uint4 ah, am, al;
  short8v b0[3], b1[3];
  auto loadA = [&](int k0) {
    float v[8];
    if (k0 + 32 <= keReal) {
      float4 t0 = *reinterpret_cast<const float4*>(ap);
      float4 t1 = *reinterpret_cast<const float4*>(ap + 4);
      v[0]=t0.x; v[1]=t0.y; v[2]=t0.z; v[3]=t0.w;
      v[4]=t1.x; v[5]=t1.y; v[6]=t1.z; v[7]=t1.w;
    } else {
#pragma unroll
      for (int i = 0; i < 8; ++i) v[i] = (k0 + akq + i < keReal) ? ap[i] : 0.0f;
    }
    split8(v, ah, am, al);
    ap += 32;
  };
  auto loadB = [&]() {
#pragma unroll
    for (int p = 0; p < 3; ++p) {
      b0[p] = *reinterpret_cast<const short8v*>(bph + (size_t)p * EWP);
      b1[p] = *reinterpret_cast<const short8v*>(bph + (size_t)p * EWP + 8);
    }
    bph += 32;
  };
  loadA(kb); loadB();
  for (int k0 = kb; k0 < kePad; k0 += 32) {
    __syncthreads();
    *reinterpret_cast<uint4*>(&As[(0 * 64 + ar) * STR + akq]) = ah;
    *reinterpret_cast<uint4*>(&As[(1 * 64 + ar) * STR + akq]) = am;
    *reinterpret_cast<uint4*>(&As[(2 * 64 + ar) * STR + akq]) = al;
#pragma unroll
    for (int p = 0; p < 3; ++p) {
      *reinterpret_cast<short8v*>(&Bs[(p * 128 + br) * STR + bkq]) = b0[p];
      *reinterpret_cast<short8v*>(&Bs[(p * 128 + br) * STR + bkq + 8]) = b1[p];
    }
    __syncthreads();
    if (k0 + 32 < kePad) { loadA(k0 + 32); loadB(); }
    mfma6<4, 64, 128>(As, Bs, wm, wn, lr, lg8, acc);
  }
  float* C = xpart + (size_t)z * NHt;
#pragma unroll
  for (int im = 0; im < 2; ++im)
#pragma unroll
    for (int in = 0; in < 4; ++in)
#pragma unroll
      for (int r = 0; r < 4; ++r)
        C[(size_t)(bm + wm + im * 16 + lg * 4 + r) * HH + bn + wn + in * 16 + lr] =
            acc[im][in][r];
}

// -------- x_hat = p0 + p1 + p2, split to 3 planes ---------------------------
__global__ __launch_bounds__(256) void combine3(const float* __restrict__ p,
                                                ushort* __restrict__ xh3) {
  int i = (blockIdx.x * 256 + threadIdx.x) * 8;
  float v[8];
#pragma unroll
  for (int e = 0; e < 8; e += 4) {
    float4 a = *reinterpret_cast<const float4*>(p + i + e);
    float4 b = *reinterpret_cast<const float4*>(p + NHt + i + e);
    float4 c = *reinterpret_cast<const float4*>(p + 2 * (size_t)NHt + i + e);
    v[e + 0] = a.x + b.x + c.x; v[e + 1] = a.y + b.y + c.y;
    v[e + 2] = a.z + b.z + c.z; v[e + 3] = a.w + b.w + c.w;
  }
  uint4 h, m, l;
  split8(v, h, m, l);
  *reinterpret_cast<uint4*>(xh3 + i) = h;
  *reinterpret_cast<uint4*>(xh3 + NHt + i) = m;
  *reinterpret_cast<uint4*>(xh3 + 2 * (size_t)NHt + i) = l;
}

// -------- xr/xz/xh = x_hat @ {Wr,Wz,Wh}^T (both sides pre-split) ------------
__global__ __launch_bounds__(256) void gemm_w36(const ushort* __restrict__ xh3,
                                                const ushort* __restrict__ w3s,
                                                float* __restrict__ xrzh) {
  const int z = blockIdx.z;
  const ushort* B = w3s + (size_t)z * 3 * HHHH;
  float* C = xrzh + (size_t)z * NHt;
  __shared__ ushort As[3 * 64 * STR];
  __shared__ ushort Bs[3 * 128 * STR];
  const int tid = threadIdx.x;
  const int bm = blockIdx.x * 64, bn = blockIdx.y * 128;
  const int wid = tid >> 6, lane = tid & 63;
  const int lr = lane & 15, lg = lane >> 4, lg8 = lg * 8;
  const int wm = (wid >> 1) * 32, wn = (wid & 1) * 64;
  const int ar = tid >> 2, akq = (tid & 3) * 8;
  const int br = tid >> 1, bkq = (tid & 1) * 16;
  const ushort* aph = xh3 + (size_t)(bm + ar) * HH + akq;
  const ushort* bph = B + (size_t)(bn + br) * HH + bkq;
  float4v acc[2][4];
#pragma unroll
  for (int i = 0; i < 2; ++i)
#pragma unroll
    for (int j = 0; j < 4; ++j) acc[i][j] = (float4v){0.f, 0.f, 0.f, 0.f};
  short8v a3[3], b0[3], b1[3];
  auto loadAll = [&]() {
#pragma unroll
    for (int p = 0; p < 3; ++p) {
      a3[p] = *reinterpret_cast<const short8v*>(aph + (size_t)p * NHt);
      b0[p] = *reinterpret_cast<const short8v*>(bph + (size_t)p * HHHH);
      b1[p] = *reinterpret_cast<const short8v*>(bph + (size_t)p * HHHH + 8);
    }
    aph += 32; bph += 32;
  };
  loadAll();
  for (int k0 = 0; k0 < HH; k0 += 32) {
    __syncthreads();
#pragma unroll
    for (int p = 0; p < 3; ++p) {
      *reinterpret_cast<short8v*>(&As[(p * 64 + ar) * STR + akq]) = a3[p];
      *reinterpret_cast<short8v*>(&Bs[(p * 128 + br) * STR + bkq]) = b0[p];
      *reinterpret_cast<short8v*>(&Bs[(p * 128 + br) * STR + bkq + 8]) = b1[p];
    }
    __syncthreads();
    if (k0 + 32 < HH) loadAll();
    mfma6<4, 64, 128>(As, Bs, wm, wn, lr, lg8, acc);
  }
#pragma unroll
  for (int im = 0; im < 2; ++im)
#pragma unroll
    for (int in = 0; in < 4; ++in)
#pragma unroll
      for (int r = 0; r < 4; ++r)
        C[(size_t)(bm + wm + im * 16 + lg * 4 + r) * HH + bn + wn + in * 16 + lr] =
            acc[im][in][r];
}

// -------- agg split-K, 32-row tiles: part[z] = adj[rows, kb:kb+AKC) @ h -----
__global__ __launch_bounds__(256) void agg6(const float* __restrict__ adj,
                                            const ushort* __restrict__ hT3,
                                            const int* __restrict__ rows,
                                            const int* __restrict__ counts,
                                            int lvl, float* __restrict__ part) {
  const int cnt = min(counts[lvl], PMAX);
  const int bm = blockIdx.x * 32;
  if (bm >= cnt) return;
  const int* rl = rows + (size_t)lvl * NNODE;
  const int kb = blockIdx.z * AKC;
  const int bn = blockIdx.y * 128;
  __shared__ ushort As[3 * 32 * STR];
  __shared__ ushort Bs[3 * 128 * STR];
  const int tid = threadIdx.x;
  const int wid = tid >> 6, lane = tid & 63;
  const int lr = lane & 15, lg = lane >> 4, lg8 = lg * 8;
  const int wn = wid * 32;
  const int ar = (tid & 127) >> 2, akq = (tid & 3) * 8;  // A: tid<128
  const int br = tid >> 1, bkq = (tid & 1) * 16;         // B: all
  int p0 = bm + ar;
  if (p0 >= cnt) p0 = cnt - 1;  // clamp: duplicate row, never stored
  const float* ap = adj + (size_t)rl[p0] * NNODE + kb + akq;
  const ushort* bph = hT3 + (size_t)(bn + br) * NNODE + kb + bkq;
  float4v acc[2][2];
#pragma unroll
  for (int i = 0; i < 2; ++i)
#pragma unroll
    for (int j = 0; j < 2; ++j) acc[i][j] = (float4v){0.f, 0.f, 0.f, 0.f};
  uint4 ah, am, al;
  short8v b0[3], b1[3];
  auto loadA = [&]() {
    float4 t0 = *reinterpret_cast<const float4*>(ap);
    float4 t1 = *reinterpret_cast<const float4*>(ap + 4);
    float v[8] = {t0.x, t0.y, t0.z, t0.w, t1.x, t1.y, t1.z, t1.w};
    split8(v, ah, am, al);
    ap += 32;
  };
  auto loadB = [&]() {
#pragma unroll
    for (int p = 0; p < 3; ++p) {
      b0[p] = *reinterpret_cast<const short8v*>(bph + (size_t)p * NHt);
      b1[p] = *reinterpret_cast<const short8v*>(bph + (size_t)p * NHt + 8);
    }
    bph += 32;
  };
  if (tid < 128) loadA();
  loadB();
  for (int k0 = 0; k0 < AKC; k0 += 32) {
    __syncthreads();
    if (tid < 128) {
      *reinterpret_cast<uint4*>(&As[(0 * 32 + ar) * STR + akq]) = ah;
      *reinterpret_cast<uint4*>(&As[(1 * 32 + ar) * STR + akq]) = am;
      *reinterpret_cast<uint4*>(&As[(2 * 32 + ar) * STR + akq]) = al;
    }
#pragma unroll
    for (int p = 0; p < 3; ++p) {
      *reinterpret_cast<short8v*>(&Bs[(p * 128 + br) * STR + bkq]) = b0[p];
      *reinterpret_cast<short8v*>(&Bs[(p * 128 + br) * STR + bkq + 8]) = b1[p];
    }
    __syncthreads();
    if (k0 + 32 < AKC) {
      if (tid < 128) loadA();
      loadB();
    }
    mfma6<2, 32, 128>(As, Bs, 0, wn, lr, lg8, acc);
  }
  float* cp = part + (size_t)blockIdx.z * PMAX * HH;
#pragma unroll
  for (int im = 0; im < 2; ++im)
#pragma unroll
    for (int in = 0; in < 2; ++in)
#pragma unroll
      for (int r = 0; r < 4; ++r) {
        int p = bm + 16 * im + lg * 4 + r;
        if (p < cnt)
          cp[(size_t)p * HH + bn + wn + in * 16 + lr] = acc[im][in][r];
      }
}

// -------- hs = sum_z part[z]; write fp32 + 3-plane split --------------------
__global__ __launch_bounds__(256) void agg_reduce6(const float* __restrict__ part,
                                                   float* __restrict__ hsf,
                                                   ushort* __restrict__ hs3) {
  int id = blockIdx.x * 256 + threadIdx.x;  // PMAX*HH/4 threads
  const int zs = PMAX * HH / 4;
  const float4* q = reinterpret_cast<const float4*>(part) + id;
  float4 s = q[0];
#pragma unroll
  for (int z = 1; z < AKS; ++z) {
    float4 t = q[(size_t)z * zs];
    s.x += t.x; s.y += t.y; s.z += t.z; s.w += t.w;
  }
  reinterpret_cast<float4*>(hsf)[id] = s;
  unsigned h0, m0, l0, h1, m1, l1;
  splitpair(s.x, s.y, h0, m0, l0);
  splitpair(s.z, s.w, h1, m1, l1);
  *reinterpret_cast<uint2*>(hs3 + (size_t)id * 4) = make_uint2(h0, h1);
  *reinterpret_cast<uint2*>(hs3 + PMAX * HH + (size_t)id * 4) = make_uint2(m0, m1);
  *reinterpret_cast<uint2*>(hs3 + 2 * PMAX * HH + (size_t)id * 4) = make_uint2(l0, l1);
}

// -------- r,z gates on concat B'=[Ur;Uz]: 32x64 tiles -----------------------
__global__ __launch_bounds__(256) void gates_rz6(
    const ushort* __restrict__ hs3, const ushort* __restrict__ urz3,
    const float* __restrict__ xr, const float* __restrict__ xz,
    const float* __restrict__ hsf, const int* __restrict__ rows,
    const int* __restrict__ counts, int lvl, ushort* __restrict__ tb3,
    float* __restrict__ zb) {
  const int cnt = min(counts[lvl], PMAX);
  const int bm = blockIdx.x * 32;
  if (bm >= cnt) return;
  const int* rl = rows + (size_t)lvl * NNODE;
  const int bn = blockIdx.y * 64;  // 0..1023 over [Ur;Uz]
  __shared__ ushort As[3 * 32 * STR];
  __shared__ ushort Bs[3 * 64 * STR];
  const int tid = threadIdx.x;
  const int wid = tid >> 6, lane = tid & 63;
  const int lr = lane & 15, lg = lane >> 4, lg8 = lg * 8;
  const int wn = wid * 16;
  const int ar = (tid & 127) >> 2, akq = (tid & 3) * 8;  // A: tid<128
  const int br = tid >> 2, bkq = (tid & 3) * 8;          // B: all
  const ushort* aph = hs3 + (size_t)(bm + ar) * HH + akq;
  const ushort* bph = urz3 + (size_t)(bn + br) * HH + bkq;
  float4v acc[2][1];
  acc[0][0] = (float4v){0.f, 0.f, 0.f, 0.f};
  acc[1][0] = (float4v){0.f, 0.f, 0.f, 0.f};
  short8v a3[3], b3[3];
  auto loadA = [&]() {
#pragma unroll
    for (int p = 0; p < 3; ++p)
      a3[p] = *reinterpret_cast<const short8v*>(aph + (size_t)p * PMAX * HH);
    aph += 32;
  };
  auto loadB = [&]() {
#pragma unroll
    for (int p = 0; p < 3; ++p)
      b3[p] = *reinterpret_cast<const short8v*>(bph + (size_t)p * 2 * HHHH);
    bph += 32;
  };
  if (tid < 128) loadA();
  loadB();
  for (int k0 = 0; k0 < HH; k0 += 32) {
    __syncthreads();
    if (tid < 128) {
#pragma unroll
      for (int p = 0; p < 3; ++p)
        *reinterpret_cast<short8v*>(&As[(p * 32 + ar) * STR + akq]) = a3[p];
    }
#pragma unroll
    for (int p = 0; p < 3; ++p)
      *reinterpret_cast<short8v*>(&Bs[(p * 64 + br) * STR + bkq]) = b3[p];
    __syncthreads();
    if (k0 + 32 < HH) {
      if (tid < 128) loadA();
      loadB();
    }
    mfma6<1, 32, 64>(As, Bs, 0, wn, lr, lg8, acc);
  }
  ushort* th = tb3;
  ushort* tm = tb3 + PMAX * HH;
  ushort* tl = tb3 + 2 * PMAX * HH;
#pragma unroll
  for (int im = 0; im < 2; ++im)
#pragma unroll
    for (int r = 0; r < 4; ++r) {
      int p = bm + 16 * im + lg * 4 + r;
      if (p < cnt) {
        int col = bn + wn + lr;
        int g = rl[p];
        if (col < HH) {  // r-gate half
          float rr = sigf(xr[(size_t)g * HH + col] + acc[im][0][r]);
          float t = hsf[(size_t)p * HH + col] * rr;
          ushort h, m, l;
          split1(t, h, m, l);
          size_t idx = (size_t)p * HH + col;
          th[idx] = h; tm[idx] = m; tl[idx] = l;
        } else {  // z-gate half
          int c = col - HH;
          zb[(size_t)p * HH + c] = sigf(xz[(size_t)g * HH + c] + acc[im][0][r]);
        }
      }
    }
}

// -------- h-hat + update, 32x64 tiles ---------------------------------------
__global__ __launch_bounds__(256) void gates_h6(
    const ushort* __restrict__ tb3, const ushort* __restrict__ uh3,
    const float* __restrict__ xh, const float* __restrict__ hsf,
    const float* __restrict__ zb, const int* __restrict__ rows,
    const int* __restrict__ counts, int lvl, ushort* __restrict__ hT3) {
  const int cnt = min(counts[lvl], PMAX);
  const int bm = blockIdx.x * 32;
  if (bm >= cnt) return;
  const int* rl = rows + (size_t)lvl * NNODE;
  const int bn = blockIdx.y * 64;
  __shared__ ushort As[3 * 32 * STR];
  __shared__ ushort Bs[3 * 64 * STR];
  const int tid = threadIdx.x;
  const int wid = tid >> 6, lane = tid & 63;
  const int lr = lane & 15, lg = lane >> 4, lg8 = lg * 8;
  const int wn = wid * 16;
  const int ar = (tid & 127) >> 2, akq = (tid & 3) * 8;
  const int br = tid >> 2, bkq = (tid & 3) * 8;
  const ushort* aph = tb3 + (size_t)(bm + ar) * HH + akq;
  const ushort* bph = uh3 + (size_t)(bn + br) * HH + bkq;
  float4v acc[2][1];
  acc[0][0] = (float4v){0.f, 0.f, 0.f, 0.f};
  acc[1][0] = (float4v){0.f, 0.f, 0.f, 0.f};
  short8v a3[3], b3[3];
  auto loadA = [&]() {
#pragma unroll
    for (int p = 0; p < 3; ++p)
      a3[p] = *reinterpret_cast<const short8v*>(aph + (size_t)p * PMAX * HH);
    aph += 32;
  };
  auto loadB = [&]() {
#pragma unroll
    for (int p = 0; p < 3; ++p)
      b3[p] = *reinterpret_cast<const short8v*>(bph + (size_t)p * HHHH);
    bph += 32;
  };
  if (tid < 128) loadA();
  loadB();
  for (int k0 = 0; k0 < HH; k0 += 32) {
    __syncthreads();
    if (tid < 128) {
#pragma unroll
      for (int p = 0; p < 3; ++p)
        *reinterpret_cast<short8v*>(&As[(p * 32 + ar) * STR + akq]) = a3[p];
    }
#pragma unroll
    for (int p = 0; p < 3; ++p)
      *reinterpret_cast<short8v*>(&Bs[(p * 64 + br) * STR + bkq]) = b3[p];
    __syncthreads();
    if (k0 + 32 < HH) {
      if (tid < 128) loadA();
      loadB();
    }
    mfma6<1, 32, 64>(As, Bs, 0, wn, lr, lg8, acc);
  }
  ushort* hp = hT3;
  ushort* mp = hT3 + NHt;
  ushort* lp = hT3 + 2 * (size_t)NHt;
#pragma unroll
  for (int im = 0; im < 2; ++im)
#pragma unroll
    for (int r = 0; r < 4; ++r) {
      int p = bm + 16 * im + lg * 4 + r;
      if (p < cnt) {
        int col = bn + wn + lr;
        int g = rl[p];
        size_t idx = (size_t)p * HH + col;
        float hh = tanhf(xh[(size_t)g * HH + col] + acc[im][0][r]);
        float zz = zb[idx];
        float hv = (1.0f - zz) * hsf[idx] + zz * hh;
        ushort h, m, l;
        split1(hv, h, m, l);
        size_t tix = (size_t)col * NNODE + g;
        hp[tix] = h; mp[tix] = m; lp[tix] = l;
      }
    }
}

// -------- level L-1 closed form: h = sig(xz) * tanh(xh) ---------------------
__global__ __launch_bounds__(256) void lvl7_init(const float* __restrict__ xz,
                                                 const float* __restrict__ xh,
                                                 const int* __restrict__ rows,
                                                 const int* __restrict__ counts,
                                                 ushort* __restrict__ hT3) {
  const int cnt = min(counts[LL - 1], PMAX);
  int idx = blockIdx.x * 256 + threadIdx.x;  // PMAX*HH/8 threads
  int p = idx >> 6;
  int c0 = (idx & 63) * 8;
  if (p >= cnt) return;
  int g = rows[(size_t)(LL - 1) * NNODE + p];
  float4 z0 = *reinterpret_cast<const float4*>(xz + (size_t)g * HH + c0);
  float4 z1 = *reinterpret_cast<const float4*>(xz + (size_t)g * HH + c0 + 4);
  float4 h0 = *reinterpret_cast<const float4*>(xh + (size_t)g * HH + c0);
  float4 h1 = *reinterpret_cast<const float4*>(xh + (size_t)g * HH + c0 + 4);
  float zv[8] = {z0.x, z0.y, z0.z, z0.w, z1.x, z1.y, z1.z, z1.w};
  float hv[8] = {h0.x, h0.y, h0.z, h0.w, h1.x, h1.y, h1.z, h1.w};
#pragma unroll
  for (int i = 0; i < 8; ++i) {
    float val = sigf(zv[i]) * tanhf(hv[i]);
    ushort h, m, l;
    split1(val, h, m, l);
    size_t tix = (size_t)(c0 + i) * NNODE + g;
    hT3[tix] = h;
    hT3[NHt + tix] = m;
    hT3[2 * (size_t)NHt + tix] = l;
  }
}

// -------- decoder: 4 threads/row + shfl reduce ------------------------------
__global__ __launch_bounds__(256) void decoder6(const ushort* __restrict__ hT3,
                                                const float* __restrict__ w,
                                                const float* __restrict__ b,
                                                float* __restrict__ out) {
  int t = threadIdx.x;
  int g = blockIdx.x * 64 + (t >> 2);
  int sub = t & 3;
  float a0 = 0.f, a1 = 0.f, a2 = 0.f, a3 = 0.f;
  for (int c = sub; c < HH; c += 4) {
    size_t idx = (size_t)c * NNODE + g;
    float hv = bf2f(hT3[idx]) + bf2f(hT3[NHt + idx]) + bf2f(hT3[2 * (size_t)NHt + idx]);
    a0 = fmaf(hv, w[c], a0);
    a1 = fmaf(hv, w[HH + c], a1);
    a2 = fmaf(hv, w[2 * HH + c], a2);
    a3 = fmaf(hv, w[3 * HH + c], a3);
  }
  a0 += __shfl_down(a0, 2); a0 += __shfl_down(a0, 1);
  a1 += __shfl_down(a1, 2); a1 += __shfl_down(a1, 1);
  a2 += __shfl_down(a2, 2); a2 += __shfl_down(a2, 1);
  a3 += __shfl_down(a3, 2); a3 += __shfl_down(a3, 1);
  if (sub == 0) {
    out[(size_t)g * 4 + 0] = a0 + b[0];
    out[(size_t)g * 4 + 1] = a1 + b[1];
    out[(size_t)g * 4 + 2] = a2 + b[2];
    out[(size_t)g * 4 + 3] = a3 + b[3];
  }
}

extern "C" void kernel_launch(void* const* d_in, const int* in_sizes, int n_in,
                              void* d_out, int out_size, void* d_ws,
                              size_t ws_size, hipStream_t stream) {
  const float* x   = (const float*)d_in[0];
  const float* adj = (const float*)d_in[1];
  const int* level = (const int*)d_in[2];
  const float* E_w = (const float*)d_in[3];
  const float* Wr  = (const float*)d_in[4];
  const float* Wz  = (const float*)d_in[5];
  const float* Ur  = (const float*)d_in[6];
  const float* Uz  = (const float*)d_in[7];
  const float* Wh  = (const float*)d_in[8];
  const float* Uh  = (const float*)d_in[9];
  const float* dw  = (const float*)d_in[10];
  const float* db  = (const float*)d_in[11];

  // workspace layout (16B-aligned chunks)
  char* wp = (char*)d_ws;
  ushort* urz3 = (ushort*)wp; wp += (size_t)3 * 2 * HHHH * 2;   // 3.15 MB
  ushort* uh3  = (ushort*)wp; wp += (size_t)3 * HHHH * 2;       // 1.57 MB
  ushort* w3s  = (ushort*)wp; wp += (size_t)3 * 3 * HHHH * 2;   // 4.72 MB
  ushort* hT3  = (ushort*)wp; wp += (size_t)3 * NHt * 2;        // 12.6 MB (xh3 alias)
  float*  xrzh = (float*)wp;  wp += (size_t)3 * NHt * 4;        // 25.2 MB (xpart alias)
  // REGION: Ew3 (x_hat phase) OVERLAPS level-loop buffers (disjoint lifetimes)
  char* region = wp;
  ushort* ew3  = (ushort*)region;                               // 15.4 MB
  float*  part = (float*)region;                                // 10.5 MB
  ushort* tb3  = (ushort*)(region + (size_t)AKS * PMAX * HH * 4);      // 1.97 MB
  float*  zb   = (float*)((char*)tb3 + (size_t)3 * PMAX * HH * 2);     // 1.31 MB
  float*  hsf  = (float*)((char*)zb + (size_t)PMAX * HH * 4);          // 1.31 MB
  ushort* hs3  = (ushort*)((char*)hsf + (size_t)PMAX * HH * 4);        // 1.97 MB
  size_t regionBytes = (size_t)3 * EWP * 2;  // Ew3 = 15.4 MB
  size_t lvlBytes = (size_t)AKS * PMAX * HH * 4 + (size_t)3 * PMAX * HH * 2 +
                    (size_t)PMAX * HH * 4 + (size_t)PMAX * HH * 4 +
                    (size_t)3 * PMAX * HH * 2;  // 17.1 MB
  if (lvlBytes > regionBytes) regionBytes = lvlBytes;
  wp = region + regionBytes;
  int* counts = (int*)wp; wp += 64;
  int* rowsl  = (int*)wp; wp += (size_t)LL * NNODE * 4;
  if (ws_size < (size_t)(wp - (char*)d_ws)) return;  // ~64.4 MB

  ushort* xh3 = hT3;     // x_hat planes live before hT3 is needed
  float* xpart = xrzh;   // x_hat split-K partials (3 fp32 buffers)

  hipMemsetAsync(counts, 0, 64, stream);
  build_lists<<<(NNODE + 255) / 256, 256, 0, stream>>>(level, counts, rowsl, NNODE);
  cast_all<<<dim3(HHHH / 8 / 256, 6), 256, 0, stream>>>(Ur, Uz, Uh, Wr, Wz, Wh,
                                                        urz3, uh3, w3s);
  cast_ew<<<dim3(HH * DP / 8 / 256), 256, 0, stream>>>(E_w, ew3);
  gemm_xhat_sk<<<dim3(NNODE / 64, HH / 128, 3), 256, 0, stream>>>(x, ew3, xpart);
  combine3<<<NHt / 8 / 256, 256, 0, stream>>>(xpart, xh3);
  gemm_w36<<<dim3(NNODE / 64, HH / 128, 3), 256, 0, stream>>>(xh3, w3s, xrzh);

  const float* xr  = xrzh;
  const float* xzp = xrzh + (size_t)NHt;
  const float* xhp = xrzh + (size_t)2 * NHt;

  // xh3 is dead after gemm_w36 -> zero the region as h-state (hT3)
  hipMemsetAsync(hT3, 0, (size_t)3 * NHt * 2, stream);
  lvl7_init<<<PMAX * HH / 8 / 256, 256, 0, stream>>>(xzp, xhp, rowsl, counts, hT3);

  for (int j = LL - 2; j >= 0; --j) {
    agg6<<<dim3(PMAX / 32, HH / 128, AKS), 256, 0, stream>>>(adj, hT3, rowsl,
                                                             counts, j, part);
    agg_reduce6<<<PMAX * HH / 4 / 256, 256, 0, stream>>>(part, hsf, hs3);
    gates_rz6<<<dim3(PMAX / 32, 2 * HH / 64), 256, 0, stream>>>(
        hs3, urz3, xr, xzp, hsf, rowsl, counts, j, tb3, zb);
    gates_h6<<<dim3(PMAX / 32, HH / 64), 256, 0, stream>>>(
        tb3, uh3, xhp, hsf, zb, rowsl, counts, j, hT3);
  }
  decoder6<<<dim3(NNODE / 64), 256, 0, stream>>>(hT3, dw, db, (float*)d_out);
}